// Round 2
// baseline (1633.901 us; speedup 1.0000x reference)
//
#include <hip/hip_runtime.h>
#include <hip/hip_bf16.h>

#define DEV __device__ __forceinline__

static constexpr int LL   = 4096;   // 64x64
static constexpr int GG   = 4;      // 2 branches x 2 batch
static constexpr int CBC  = 262;    // 2*128 + 6
static constexpr int BSTR = 264;    // padded bct row stride (floats) -> 1056B, 16B-aligned

DEV int map_l(int s, int k) {
    // spatial index l for scan position s in direction k (involution)
    int m = (k & 2) ? (4095 - s) : s;
    if (k & 1) m = ((m & 63) << 6) | (m >> 6);
    return m;
}
DEV float silu_f(float x) { return x / (1.f + __expf(-x)); }

__global__ void sentinel_k(float* out) { out[0] = 1e30f; }

// ---------------- generic f32 GEMM: C[M x N] = act(A * B), A row-major,
// rows < 8192 from A0, rows >= 8192 from A1 (local row = row & 8191) ----------------
template<int ACT>
__global__ __launch_bounds__(256) void gemm_k(
    const float* __restrict__ A0, const float* __restrict__ A1,
    const float* __restrict__ B, float* __restrict__ C,
    int N, int Kd)
{
    __shared__ float As[64][33];
    __shared__ float Bs[32][65];
    int i0 = blockIdx.y * 64;
    int j0 = blockIdx.x * 64;
    int t = threadIdx.x;
    int tr = t >> 4, tc = t & 15;
    float acc[4][4] = {};
    for (int k0 = 0; k0 < Kd; k0 += 32) {
        #pragma unroll
        for (int r = 0; r < 8; ++r) {
            int fi = t + 256 * r;
            int row = fi >> 5, kk = fi & 31;
            int grow = i0 + row;
            const float* Ap = (grow < 8192) ? A0 : A1;
            As[row][kk] = Ap[(size_t)(grow & 8191) * Kd + k0 + kk];
        }
        #pragma unroll
        for (int r = 0; r < 8; ++r) {
            int fi = t + 256 * r;
            int kr = fi >> 6, col = fi & 63;
            int gcol = j0 + col;
            Bs[kr][col] = (gcol < N) ? B[(size_t)(k0 + kr) * N + gcol] : 0.f;
        }
        __syncthreads();
        #pragma unroll
        for (int kk = 0; kk < 32; ++kk) {
            float a[4], b[4];
            #pragma unroll
            for (int ii = 0; ii < 4; ++ii) a[ii] = As[tr * 4 + ii][kk];
            #pragma unroll
            for (int jj = 0; jj < 4; ++jj) b[jj] = Bs[kk][tc * 4 + jj];
            #pragma unroll
            for (int ii = 0; ii < 4; ++ii)
                #pragma unroll
                for (int jj = 0; jj < 4; ++jj) acc[ii][jj] += a[ii] * b[jj];
        }
        __syncthreads();
    }
    #pragma unroll
    for (int ii = 0; ii < 4; ++ii) {
        int row = i0 + tr * 4 + ii;
        #pragma unroll
        for (int jj = 0; jj < 4; ++jj) {
            int col = j0 + tc * 4 + jj;
            if (col < N) {
                float v = acc[ii][jj];
                if (ACT) v = silu_f(v);
                C[(size_t)row * N + col] = v;
            }
        }
    }
}

// ---------------- depthwise 3x3 conv (pad 1) + bias + silu ----------------
__global__ void dwconv_k(const float* __restrict__ in, const float* __restrict__ w,
                         const float* __restrict__ bias, float* __restrict__ out,
                         int Cin, int Cout)
{
    int idx = blockIdx.x * 256 + threadIdx.x;
    int total = GG * LL * Cin;
    if (idx >= total) return;
    int c = idx % Cin;
    int l = (idx / Cin) % LL;
    int g = idx / (Cin * LL);
    int h = l >> 6, ww = l & 63;
    float acc = bias[c];
    #pragma unroll
    for (int dy = 0; dy < 3; ++dy) {
        int hh = h + dy - 1;
        if ((unsigned)hh >= 64u) continue;
        #pragma unroll
        for (int dx = 0; dx < 3; ++dx) {
            int wx = ww + dx - 1;
            if ((unsigned)wx >= 64u) continue;
            acc += in[((size_t)g * LL + (hh << 6) + wx) * Cin + c] * w[c * 9 + dy * 3 + dx];
        }
    }
    out[((size_t)g * LL + l) * Cout + c] = silu_f(acc);
}

// ---------------- dt softplus + per-chunk inclusive cumsum of dt*A ----------------
__global__ __launch_bounds__(256) void dtscan_k(
    const float* __restrict__ bct, const float* __restrict__ dt_bias,
    const float* __restrict__ A_logs, float* __restrict__ dt_arr,
    float* __restrict__ ac_arr, float* __restrict__ cdecay)
{
    __shared__ float sbuf[256];
    int g = blockIdx.x >> 4, c = blockIdx.x & 15;
    int t = threadIdx.x;
    int s = c * 256 + t;
    for (int ht = 0; ht < 24; ++ht) {
        int k = ht / 6, h = ht % 6;
        int l = map_l(s, k);
        float raw = bct[((size_t)g * LL + l) * BSTR + 256 + h] + dt_bias[ht];
        float dtv = raw > 20.f ? raw : log1pf(__expf(raw));
        float dA = dtv * (-__expf(A_logs[ht]));
        sbuf[t] = dA;
        __syncthreads();
        for (int off = 1; off < 256; off <<= 1) {
            float add = (t >= off) ? sbuf[t - off] : 0.f;
            __syncthreads();
            sbuf[t] += add;
            __syncthreads();
        }
        float cum = sbuf[t];
        size_t base = ((size_t)g * 24 + ht) * LL + s;
        dt_arr[base] = dtv;
        ac_arr[base] = cum;
        if (t == 255) cdecay[(g * 24 + ht) * 16 + c] = __expf(cum);
        __syncthreads();
    }
}

// ---------------- CB[gc][i][j] = sum_n C[i,n]*B[j,n]; B/C gathered from bct ----------------
__global__ __launch_bounds__(256) void cb_k(const float* __restrict__ bct,
                                            float* __restrict__ CB)
{
    __shared__ float As[64][33], Bs[64][33];
    int bt = blockIdx.y;                       // g*16+c
    int g = bt >> 4, c = bt & 15;
    int ti = (blockIdx.x >> 2) * 64, tj = (blockIdx.x & 3) * 64;
    int t = threadIdx.x;
    int tr = t >> 4, tc = t & 15;
    float acc[4][4] = {};
    for (int k0 = 0; k0 < 512; k0 += 32) {
        int kd = k0 >> 7, nn0 = k0 & 127;
        #pragma unroll
        for (int r = 0; r < 8; ++r) {
            int fi = t + 256 * r;
            int row = fi >> 5, kk = fi & 31;
            int li = map_l(c * 256 + ti + row, kd);
            int lj = map_l(c * 256 + tj + row, kd);
            As[row][kk] = bct[((size_t)g * LL + li) * BSTR + 128 + nn0 + kk];  // C
            Bs[row][kk] = bct[((size_t)g * LL + lj) * BSTR + nn0 + kk];        // B
        }
        __syncthreads();
        #pragma unroll
        for (int kk = 0; kk < 32; ++kk) {
            float a[4], b[4];
            #pragma unroll
            for (int ii = 0; ii < 4; ++ii) a[ii] = As[tr * 4 + ii][kk];
            #pragma unroll
            for (int jj = 0; jj < 4; ++jj) b[jj] = Bs[tc * 4 + jj][kk];
            #pragma unroll
            for (int ii = 0; ii < 4; ++ii)
                #pragma unroll
                for (int jj = 0; jj < 4; ++jj) acc[ii][jj] += a[ii] * b[jj];
        }
        __syncthreads();
    }
    float* outp = CB + (size_t)bt * 65536;
    #pragma unroll
    for (int ii = 0; ii < 4; ++ii)
        #pragma unroll
        for (int jj = 0; jj < 4; ++jj)
            outp[(size_t)(ti + tr * 4 + ii) * 256 + tj + tc * 4 + jj] = acc[ii][jj];
}

// ---------------- per-(g,chunk,head): states[p,n] = sum_j w_j * x[j,p] * B[j,n] ----------------
__global__ __launch_bounds__(256) void states_k(
    const float* __restrict__ xs_t, const float* __restrict__ bct,
    const float* __restrict__ dt_arr, const float* __restrict__ ac_arr,
    __hip_bfloat16* __restrict__ states)
{
    __shared__ float Bsh[16][512];
    __shared__ float xsh[16][64];
    __shared__ float wsh[16];
    int bid = blockIdx.x;
    int ht = bid % 24;
    int gc = bid / 24;
    int c = gc & 15, g = gc >> 4;
    int k = ht / 6;
    int c0 = (ht % 6) * 64;
    int t = threadIdx.x;
    int p0 = (t >> 5) * 8;
    int n0 = (t & 31) * 16;
    const float* dtp = dt_arr + ((size_t)g * 24 + ht) * LL;
    const float* acp = ac_arr + ((size_t)g * 24 + ht) * LL;
    int sbase = c * 256;
    float ac_last = acp[sbase + 255];
    float acc[8][16] = {};
    for (int jt = 0; jt < 256; jt += 16) {
        #pragma unroll
        for (int r = 0; r < 8; ++r) {            // 16*512 floats = 2048 f4
            int fi = t + 256 * r;
            int jl = fi >> 7, nf = (fi & 127) << 2;   // 4 consecutive n, same direction block
            int kd = nf >> 7, nn = nf & 127;
            int l = map_l(sbase + jt + jl, kd);
            *(float4*)&Bsh[jl][nf] =
                *(const float4*)&bct[((size_t)g * LL + l) * BSTR + nn];
        }
        {                                        // 16*64 floats = 256 f4
            int jl = t >> 4, pf = (t & 15) << 2;
            int l = map_l(sbase + jt + jl, k);
            *(float4*)&xsh[jl][pf] =
                *(const float4*)&xs_t[((size_t)g * LL + l) * 384 + c0 + pf];
        }
        if (t < 16) {
            int j = sbase + jt + t;
            wsh[t] = __expf(ac_last - acp[j]) * dtp[j];
        }
        __syncthreads();
        for (int jl = 0; jl < 16; ++jl) {
            float wv = wsh[jl];
            float xv[8], bv[16];
            #pragma unroll
            for (int pp = 0; pp < 8; ++pp) xv[pp] = wv * xsh[jl][p0 + pp];
            #pragma unroll
            for (int nn = 0; nn < 16; ++nn) bv[nn] = Bsh[jl][n0 + nn];
            #pragma unroll
            for (int pp = 0; pp < 8; ++pp)
                #pragma unroll
                for (int nn = 0; nn < 16; ++nn)
                    acc[pp][nn] += xv[pp] * bv[nn];
        }
        __syncthreads();
    }
    __hip_bfloat16* outp = states + ((size_t)gc * 24 + ht) * 32768;
    #pragma unroll
    for (int pp = 0; pp < 8; ++pp) {
        union { __hip_bfloat16 h[16]; float4 f[2]; } u;
        #pragma unroll
        for (int nn = 0; nn < 16; ++nn) u.h[nn] = __float2bfloat16(acc[pp][nn]);
        float4* dst = (float4*)&outp[(size_t)(p0 + pp) * 512 + n0];
        dst[0] = u.f[0]; dst[1] = u.f[1];
    }
}

// ---------------- inter-chunk scan, in place: states[c] <- S_before(c) ----------------
__global__ void scan_k(__hip_bfloat16* __restrict__ states, const float* __restrict__ cdecay)
{
    int idx = blockIdx.x * 256 + threadIdx.x;   // G*24*64*512 = 3,145,728
    int g = idx / 786432;
    int r = idx - g * 786432;
    int ht = r >> 15;
    int pn = r & 32767;
    const float* cd = cdecay + (g * 24 + ht) * 16;
    __hip_bfloat16* base = states + ((size_t)g * 384 + ht) * 32768 + pn;
    float S = 0.f;
    #pragma unroll
    for (int c2 = 0; c2 < 16; ++c2) {
        __hip_bfloat16* p = base + (size_t)c2 * 786432;
        float tmp = __bfloat162float(*p);
        *p = __float2bfloat16(S);
        S = S * cd[c2] + tmp;
    }
}

// ---------------- per-(g,chunk,head) y: causal M*x + exp(ac_i)*C*prev^T + Ds*x ----------------
__global__ __launch_bounds__(256) void yk(
    const float* __restrict__ xs_t, const float* __restrict__ bct,
    const float* __restrict__ CBm, const __hip_bfloat16* __restrict__ prev,
    const float* __restrict__ dt_arr, const float* __restrict__ ac_arr,
    const float* __restrict__ Ds, __hip_bfloat16* __restrict__ y_ssd)
{
    __shared__ float xsh[64][64];
    __shared__ float pT[32][68];
    __shared__ float dts[256], acs[256];
    int bid = blockIdx.x;
    int ht = bid % 24;
    int gc = bid / 24;
    int c = gc & 15, g = gc >> 4;
    int k = ht / 6;
    int c0 = (ht % 6) * 64;
    int t = threadIdx.x;
    int i0 = t >> 2;                 // wave w owns i in [64w, 64w+63]
    int p0 = (t & 3) * 16;
    int wave = t >> 6;
    const float* dtp = dt_arr + ((size_t)g * 24 + ht) * LL + c * 256;
    const float* acp = ac_arr + ((size_t)g * 24 + ht) * LL + c * 256;
    dts[t] = dtp[t];
    acs[t] = acp[t];
    __syncthreads();
    float aci[4], ei[4];
    #pragma unroll
    for (int ii = 0; ii < 4; ++ii) {
        aci[ii] = acs[i0 * 4 + ii];
        ei[ii] = __expf(aci[ii]);
    }
    float acc[4][16] = {};
    const float* CBb = CBm + (size_t)gc * 65536;
    for (int jt = 0; jt < 256; jt += 64) {
        #pragma unroll
        for (int r = 0; r < 4; ++r) {           // 64*64 floats = 1024 f4
            int fi = t + 256 * r;
            int jl = fi >> 4, pf = (fi & 15) << 2;
            int l = map_l(c * 256 + jt + jl, k);
            *(float4*)&xsh[jl][pf] =
                *(const float4*)&xs_t[((size_t)g * LL + l) * 384 + c0 + pf];
        }
        __syncthreads();
        if (jt < wave * 64) {
            // full tile: every j here is < every i owned by this wave
            for (int jl = 0; jl < 64; ++jl) {
                int j = jt + jl;
                float dtj = dts[j], acj = acs[j];
                float xv[16];
                #pragma unroll
                for (int pp = 0; pp < 16; ++pp) xv[pp] = xsh[jl][p0 + pp];
                #pragma unroll
                for (int ii = 0; ii < 4; ++ii) {
                    float coef = CBb[(size_t)(i0 * 4 + ii) * 256 + j] *
                                 __expf(aci[ii] - acj) * dtj;
                    #pragma unroll
                    for (int pp = 0; pp < 16; ++pp) acc[ii][pp] += coef * xv[pp];
                }
            }
        } else if (jt == wave * 64) {
            // diagonal tile: predicate j <= i
            for (int jl = 0; jl < 64; ++jl) {
                int j = jt + jl;
                float dtj = dts[j], acj = acs[j];
                float xv[16];
                #pragma unroll
                for (int pp = 0; pp < 16; ++pp) xv[pp] = xsh[jl][p0 + pp];
                #pragma unroll
                for (int ii = 0; ii < 4; ++ii) {
                    int i = i0 * 4 + ii;
                    if (j <= i) {
                        float coef = CBb[(size_t)i * 256 + j] *
                                     __expf(aci[ii] - acj) * dtj;
                        #pragma unroll
                        for (int pp = 0; pp < 16; ++pp) acc[ii][pp] += coef * xv[pp];
                    }
                }
            }
        }
        __syncthreads();
    }
    // term2: exp(ac_i) * sum_n C[i,n] * prev[p,n]; C gathered from bct per direction
    const __hip_bfloat16* pv = prev + ((size_t)gc * 24 + ht) * 32768;
    for (int kd2 = 0; kd2 < 4; ++kd2) {
        const float* crow[4];
        #pragma unroll
        for (int ii = 0; ii < 4; ++ii) {
            int l = map_l(c * 256 + i0 * 4 + ii, kd2);
            crow[ii] = bct + ((size_t)g * LL + l) * BSTR + 128;
        }
        for (int nt = 0; nt < 128; nt += 32) {
            #pragma unroll
            for (int r = 0; r < 8; ++r) {           // 32*64 = 2048 elems
                int fi = t + 256 * r;
                int nn = fi & 31, p = fi >> 5;
                pT[nn][p] = __bfloat162float(pv[(size_t)p * 512 + kd2 * 128 + nt + nn]);
            }
            __syncthreads();
            for (int nn = 0; nn < 32; ++nn) {
                float a[4], b[16];
                #pragma unroll
                for (int ii = 0; ii < 4; ++ii)
                    a[ii] = ei[ii] * crow[ii][nt + nn];
                #pragma unroll
                for (int pp = 0; pp < 16; ++pp) b[pp] = pT[nn][p0 + pp];
                #pragma unroll
                for (int ii = 0; ii < 4; ++ii)
                    #pragma unroll
                    for (int pp = 0; pp < 16; ++pp) acc[ii][pp] += a[ii] * b[pp];
            }
            __syncthreads();
        }
    }
    // term3 + write y_ssd[g][s][ht][p] (bf16)
    float Dsv = Ds[ht];
    __hip_bfloat16* yb = y_ssd + (((size_t)g * LL + c * 256) * 24 + ht) * 64;
    #pragma unroll
    for (int ii = 0; ii < 4; ++ii) {
        int i = i0 * 4 + ii;
        int l = map_l(c * 256 + i, k);
        const float* xr = &xs_t[((size_t)g * LL + l) * 384 + c0 + p0];
        __hip_bfloat16* yr = yb + (size_t)i * 1536 + p0;
        #pragma unroll
        for (int pp = 0; pp < 16; ++pp)
            yr[pp] = __float2bfloat16(acc[ii][pp] + Dsv * xr[pp]);
    }
}

// ---------------- merge 4 directions + gate + RMSNorm ----------------
__global__ __launch_bounds__(128) void gate_k(
    const __hip_bfloat16* __restrict__ y_ssd, const float* __restrict__ z_silu,
    const float* __restrict__ norm_w, float* __restrict__ gn)
{
    int g = blockIdx.x >> 12;
    int l = blockIdx.x & 4095;
    int t = threadIdx.x;
    int s1 = ((l & 63) << 6) | (l >> 6);
    int s2 = 4095 - l;
    int s3 = ((s2 & 63) << 6) | (s2 >> 6);
    const __hip_bfloat16* y0 = y_ssd + ((size_t)g * LL + l)  * 1536;
    const __hip_bfloat16* y1 = y_ssd + ((size_t)g * LL + s1) * 1536 + 384;
    const __hip_bfloat16* y2 = y_ssd + ((size_t)g * LL + s2) * 1536 + 768;
    const __hip_bfloat16* y3 = y_ssd + ((size_t)g * LL + s3) * 1536 + 1152;
    const float* zp = z_silu + ((size_t)g * LL + l) * 384;
    float gc[3]; float ssq = 0.f;
    #pragma unroll
    for (int q = 0; q < 3; ++q) {
        int cdim = t + 128 * q;
        float yf = __bfloat162float(y0[cdim]) + __bfloat162float(y1[cdim]) +
                   __bfloat162float(y2[cdim]) + __bfloat162float(y3[cdim]);
        float v = yf * zp[cdim];
        gc[q] = v;
        ssq += v * v;
    }
    float v = ssq;
    #pragma unroll
    for (int off = 32; off > 0; off >>= 1) v += __shfl_down(v, off);
    __shared__ float tot[2];
    if ((t & 63) == 0) tot[t >> 6] = v;
    __syncthreads();
    float rs = rsqrtf((tot[0] + tot[1]) * (1.f / 384.f) + 1e-5f);
    float* gp = gn + ((size_t)g * LL + l) * 384;
    #pragma unroll
    for (int q = 0; q < 3; ++q) {
        int cdim = t + 128 * q;
        gp[cdim] = gc[q] * rs * norm_w[cdim];
    }
}

extern "C" void kernel_launch(void* const* d_in, const int* in_sizes, int n_in,
                              void* d_out, int out_size, void* d_ws, size_t ws_size,
                              hipStream_t stream)
{
    const float* u1      = (const float*)d_in[0];
    const float* u2      = (const float*)d_in[1];
    const float* u21     = (const float*)d_in[2];   // u2_cat_u1
    const float* u12     = (const float*)d_in[3];   // u1_cat_u2
    const float* W_skip  = (const float*)d_in[4];
    const float* W_xs    = (const float*)d_in[5];
    const float* W_bcdt  = (const float*)d_in[6];
    const float* cxw     = (const float*)d_in[7];
    const float* cxb     = (const float*)d_in[8];
    const float* cbw     = (const float*)d_in[9];
    const float* cbb     = (const float*)d_in[10];
    const float* dt_bias = (const float*)d_in[11];
    const float* A_logs  = (const float*)d_in[12];
    const float* Ds      = (const float*)d_in[13];
    const float* norm_w  = (const float*)d_in[14];
    const float* W_out   = (const float*)d_in[15];
    float* out = (float*)d_out;

    char* w = (char*)d_ws;
    // static layout (bytes); aliases noted
    size_t o_y   = 0;                        // y_ssd bf16: 4*4096*1536*2 = 50,331,648
    size_t o_st  = o_y  + 50331648;          // states bf16: 64*24*64*512*2 = 100,663,296
    size_t o_xs  = o_st + 100663296;         // xs_t f32: 4*4096*384*4 = 25,165,824
    size_t o_bct = o_xs + 25165824;          // bct f32 padded: 4*4096*264*4 = 17,301,504
    size_t o_z   = o_bct + 17301504;         // z_silu f32: 25,165,824
    size_t o_dt  = o_z  + 25165824;          // dt_arr: 4*24*4096*4 = 1,572,864
    size_t o_ac  = o_dt + 1572864;           // ac_arr: 1,572,864
    size_t o_cd  = o_ac + 1572864;           // cdecay: 4*24*16*4 = 6,144 (pad 8,192)
    size_t o_cb  = o_cd + 8192;              // CBm f32: 64*65536*4 = 16,777,216
    size_t total = o_cb + 16777216;          // = 238,559,232 B (~227.5 MiB)
    if (total > ws_size) {
        sentinel_k<<<1, 1, 0, stream>>>(out);   // absmax ~1e30 => workspace too small
        return;
    }
    __hip_bfloat16* y_ssd  = (__hip_bfloat16*)(w + o_y);
    __hip_bfloat16* states = (__hip_bfloat16*)(w + o_st);
    float* xs_t   = (float*)(w + o_xs);
    float* bct    = (float*)(w + o_bct);
    float* z_silu = (float*)(w + o_z);
    float* dt_arr = (float*)(w + o_dt);
    float* ac_arr = (float*)(w + o_ac);
    float* cdecay = (float*)(w + o_cd);
    float* CBm    = (float*)(w + o_cb);
    // transient aliases (dead before their hosts are written)
    float* pre_xs = (float*)(w + o_y);              // inside y_ssd region
    float* pre_bc = (float*)(w + o_y + 25165824);   // inside y_ssd region
    float* gn     = (float*)(w + o_st);             // inside states region (dead after yk)

    dim3 blk(256);
    // 1. input GEMMs (rows: g = branch*2 + batch, l row-major)
    gemm_k<1><<<dim3(6, 256), blk, 0, stream>>>(u1, u2, W_skip, z_silu, 384, 192);
    gemm_k<0><<<dim3(6, 256), blk, 0, stream>>>(u1, u2, W_xs, pre_xs, 384, 192);
    gemm_k<0><<<dim3(5, 256), blk, 0, stream>>>(u21, u12, W_bcdt, pre_bc, CBC, 192);
    // 2. depthwise conv + silu
    dwconv_k<<<dim3((GG * LL * 384) / 256), blk, 0, stream>>>(pre_xs, cxw, cxb, xs_t, 384, 384);
    dwconv_k<<<dim3((GG * LL * CBC + 255) / 256), blk, 0, stream>>>(pre_bc, cbw, cbb, bct, CBC, BSTR);
    // 3. dt softplus + per-chunk cumsum of dt*A
    dtscan_k<<<dim3(64), blk, 0, stream>>>(bct, dt_bias, A_logs, dt_arr, ac_arr, cdecay);
    // 4. CB = C * B^T per (g, chunk), gathered from bct
    cb_k<<<dim3(16, 64), blk, 0, stream>>>(bct, CBm);
    // 5. per-chunk states
    states_k<<<dim3(1536), blk, 0, stream>>>(xs_t, bct, dt_arr, ac_arr, states);
    // 6. inter-chunk scan (in place -> prev states)
    scan_k<<<dim3(12288), blk, 0, stream>>>(states, cdecay);
    // 7. y = causal M*x + exp(ac)*C*prev^T + Ds*x
    yk<<<dim3(1536), blk, 0, stream>>>(xs_t, bct, CBm, states, dt_arr, ac_arr, Ds, y_ssd);
    // 8. merge directions + gate + RMSNorm
    gate_k<<<dim3(16384), dim3(128), 0, stream>>>(y_ssd, z_silu, norm_w, gn);
    // 9. output GEMM
    gemm_k<0><<<dim3(3, 256), blk, 0, stream>>>(gn, gn + (size_t)8192 * 384, W_out, out, 192, 384);
}

// Round 3
// 780.396 us; speedup vs baseline: 2.0937x; 2.0937x over previous
//
#include <hip/hip_runtime.h>
#include <hip/hip_bf16.h>

#define DEV __device__ __forceinline__

static constexpr int LL   = 4096;   // 64x64
static constexpr int GG   = 4;      // 2 branches x 2 batch
static constexpr int CBC  = 262;    // 2*128 + 6
static constexpr int BSTR = 264;    // padded bct row stride (floats), 16B-aligned

typedef float f32x4  __attribute__((ext_vector_type(4)));
typedef short bf16x8 __attribute__((ext_vector_type(8)));
typedef short bf16x4v __attribute__((ext_vector_type(4)));

DEV int map_l(int s, int k) {
    int m = (k & 2) ? (4095 - s) : s;
    if (k & 1) m = ((m & 63) << 6) | (m >> 6);
    return m;
}
DEV float silu_f(float x) { return x / (1.f + __expf(-x)); }
DEV short f2bf(float f) {
    union { __hip_bfloat16 h; short s; } u;
    u.h = __float2bfloat16(f);
    return u.s;
}
DEV float bf2f(short s) {
    return __uint_as_float(((unsigned)(unsigned short)s) << 16);
}
DEV bf16x8 pack8(float4 a, float4 b) {
    bf16x8 r;
    r[0]=f2bf(a.x); r[1]=f2bf(a.y); r[2]=f2bf(a.z); r[3]=f2bf(a.w);
    r[4]=f2bf(b.x); r[5]=f2bf(b.y); r[6]=f2bf(b.z); r[7]=f2bf(b.w);
    return r;
}
DEV bf16x8 pack8s(float4 a, float4 b, float s) {
    bf16x8 r;
    r[0]=f2bf(a.x*s); r[1]=f2bf(a.y*s); r[2]=f2bf(a.z*s); r[3]=f2bf(a.w*s);
    r[4]=f2bf(b.x*s); r[5]=f2bf(b.y*s); r[6]=f2bf(b.z*s); r[7]=f2bf(b.w*s);
    return r;
}
DEV void store16(__hip_bfloat16* p, const float* v) {
    bf16x8 a, b;
    #pragma unroll
    for (int e = 0; e < 8; ++e) { a[e] = f2bf(v[e]); b[e] = f2bf(v[8+e]); }
    *(bf16x8*)p = a;
    *((bf16x8*)p + 1) = b;
}

__global__ void sentinel_k(float* out) { out[0] = 1e30f; }

// ---------------- generic f32 GEMM: C[M x N] = act(A * B) ----------------
DEV void storeT(float v, float* p) { *p = v; }
DEV void storeT(float v, __hip_bfloat16* p) { *p = __float2bfloat16(v); }

template<int ACT, typename OutT>
__global__ __launch_bounds__(256) void gemm_k(
    const float* __restrict__ A0, const float* __restrict__ A1,
    const float* __restrict__ B, OutT* __restrict__ C,
    int N, int Kd)
{
    __shared__ float As[64][33];
    __shared__ float Bs[32][65];
    int i0 = blockIdx.y * 64;
    int j0 = blockIdx.x * 64;
    int t = threadIdx.x;
    int tr = t >> 4, tc = t & 15;
    float acc[4][4] = {};
    for (int k0 = 0; k0 < Kd; k0 += 32) {
        #pragma unroll
        for (int r = 0; r < 8; ++r) {
            int fi = t + 256 * r;
            int row = fi >> 5, kk = fi & 31;
            int grow = i0 + row;
            const float* Ap = (grow < 8192) ? A0 : A1;
            As[row][kk] = Ap[(size_t)(grow & 8191) * Kd + k0 + kk];
        }
        #pragma unroll
        for (int r = 0; r < 8; ++r) {
            int fi = t + 256 * r;
            int kr = fi >> 6, col = fi & 63;
            int gcol = j0 + col;
            Bs[kr][col] = (gcol < N) ? B[(size_t)(k0 + kr) * N + gcol] : 0.f;
        }
        __syncthreads();
        #pragma unroll
        for (int kk = 0; kk < 32; ++kk) {
            float a[4], b[4];
            #pragma unroll
            for (int ii = 0; ii < 4; ++ii) a[ii] = As[tr * 4 + ii][kk];
            #pragma unroll
            for (int jj = 0; jj < 4; ++jj) b[jj] = Bs[kk][tc * 4 + jj];
            #pragma unroll
            for (int ii = 0; ii < 4; ++ii)
                #pragma unroll
                for (int jj = 0; jj < 4; ++jj) acc[ii][jj] += a[ii] * b[jj];
        }
        __syncthreads();
    }
    #pragma unroll
    for (int ii = 0; ii < 4; ++ii) {
        int row = i0 + tr * 4 + ii;
        #pragma unroll
        for (int jj = 0; jj < 4; ++jj) {
            int col = j0 + tc * 4 + jj;
            if (col < N) {
                float v = acc[ii][jj];
                if (ACT) v = silu_f(v);
                storeT(v, &C[(size_t)row * N + col]);
            }
        }
    }
}

// ---------------- depthwise 3x3 conv (pad 1) + bias + silu ----------------
__global__ void dwconv_k(const float* __restrict__ in, const float* __restrict__ w,
                         const float* __restrict__ bias, float* __restrict__ out,
                         int Cin, int Cout)
{
    int idx = blockIdx.x * 256 + threadIdx.x;
    int total = GG * LL * Cin;
    if (idx >= total) return;
    int c = idx % Cin;
    int l = (idx / Cin) % LL;
    int g = idx / (Cin * LL);
    int h = l >> 6, ww = l & 63;
    float acc = bias[c];
    #pragma unroll
    for (int dy = 0; dy < 3; ++dy) {
        int hh = h + dy - 1;
        if ((unsigned)hh >= 64u) continue;
        #pragma unroll
        for (int dx = 0; dx < 3; ++dx) {
            int wx = ww + dx - 1;
            if ((unsigned)wx >= 64u) continue;
            acc += in[((size_t)g * LL + (hh << 6) + wx) * Cin + c] * w[c * 9 + dy * 3 + dx];
        }
    }
    out[((size_t)g * LL + l) * Cout + c] = silu_f(acc);
}

// ---------------- xs transpose/gather: XtG[g][kd][pc 384][s 4096] bf16 ----------------
__global__ __launch_bounds__(256) void xt_k(const float* __restrict__ xs_t,
                                            __hip_bfloat16* __restrict__ XtG)
{
    __shared__ float ls[16][17][17];
    int bid = blockIdx.x;                 // 24 pct x 4 wt x 4 ht x 4 g = 1536
    int pct = bid % 24;
    int rest = bid / 24;
    int wt = rest & 3, ht2 = (rest >> 2) & 3, g = rest >> 4;
    int h0 = ht2 * 16, w0 = wt * 16, pc0 = pct * 16;
    int t = threadIdx.x;
    int pcl = t & 15, hwb = t >> 4;
    #pragma unroll
    for (int r = 0; r < 16; ++r) {
        int hw = hwb + r * 16;
        int h = hw >> 4, w2 = hw & 15;
        ls[h][w2][pcl] = xs_t[((size_t)g * LL + (h0 + h) * 64 + (w0 + w2)) * 384 + pc0 + pcl];
    }
    __syncthreads();
    int pc = t >> 4, q = t & 15;
    float v[16];
    size_t rowbase;
    // kd0: s = (h0+q)*64 + w0 + e
    #pragma unroll
    for (int e = 0; e < 16; ++e) v[e] = ls[q][e][pc];
    rowbase = ((size_t)(g * 4 + 0) * 384 + pc0 + pc) * 4096;
    store16(XtG + rowbase + (h0 + q) * 64 + w0, v);
    // kd1: s = (w0+q)*64 + h0 + e
    #pragma unroll
    for (int e = 0; e < 16; ++e) v[e] = ls[e][q][pc];
    rowbase = ((size_t)(g * 4 + 1) * 384 + pc0 + pc) * 4096;
    store16(XtG + rowbase + (w0 + q) * 64 + h0, v);
    // kd2: s = 4095 - (h0+q)*64 - w0 - 15 + e
    #pragma unroll
    for (int e = 0; e < 16; ++e) v[e] = ls[q][15 - e][pc];
    rowbase = ((size_t)(g * 4 + 2) * 384 + pc0 + pc) * 4096;
    store16(XtG + rowbase + 4095 - (h0 + q) * 64 - w0 - 15, v);
    // kd3: s = 4095 - (w0+q)*64 - h0 - 15 + e
    #pragma unroll
    for (int e = 0; e < 16; ++e) v[e] = ls[15 - e][q][pc];
    rowbase = ((size_t)(g * 4 + 3) * 384 + pc0 + pc) * 4096;
    store16(XtG + rowbase + 4095 - (w0 + q) * 64 - h0 - 15, v);
}

// ---------------- B transpose/gather: Bt[g][n 512][s 4096] bf16 ----------------
__global__ __launch_bounds__(256) void bt_k(const float* __restrict__ bct,
                                            __hip_bfloat16* __restrict__ Bt)
{
    __shared__ float ls[16][17][17];
    int bid = blockIdx.x;                 // 32 nt x 4 wt x 4 ht x 4 g = 2048
    int nt = bid & 31;
    int rest = bid >> 5;
    int wt = rest & 3, ht2 = (rest >> 2) & 3, g = rest >> 4;
    int h0 = ht2 * 16, w0 = wt * 16;
    int kd = nt >> 3, ch0 = (nt & 7) * 16;
    int t = threadIdx.x;
    int cl = t & 15, hwb = t >> 4;
    #pragma unroll
    for (int r = 0; r < 16; ++r) {
        int hw = hwb + r * 16;
        int h = hw >> 4, w2 = hw & 15;
        ls[h][w2][cl] = bct[((size_t)g * LL + (h0 + h) * 64 + (w0 + w2)) * BSTR + ch0 + cl];
    }
    __syncthreads();
    int pc = t >> 4, q = t & 15;
    int n = nt * 16 + pc;
    __hip_bfloat16* rowp = Bt + ((size_t)g * 512 + n) * 4096;
    float v[16];
    if (kd == 0) {
        #pragma unroll
        for (int e = 0; e < 16; ++e) v[e] = ls[q][e][pc];
        store16(rowp + (h0 + q) * 64 + w0, v);
    } else if (kd == 1) {
        #pragma unroll
        for (int e = 0; e < 16; ++e) v[e] = ls[e][q][pc];
        store16(rowp + (w0 + q) * 64 + h0, v);
    } else if (kd == 2) {
        #pragma unroll
        for (int e = 0; e < 16; ++e) v[e] = ls[q][15 - e][pc];
        store16(rowp + 4095 - (h0 + q) * 64 - w0 - 15, v);
    } else {
        #pragma unroll
        for (int e = 0; e < 16; ++e) v[e] = ls[15 - e][q][pc];
        store16(rowp + 4095 - (w0 + q) * 64 - h0 - 15, v);
    }
}

// ---------------- dt softplus + per-chunk inclusive cumsum of dt*A ----------------
__global__ __launch_bounds__(256) void dtscan_k(
    const float* __restrict__ bct, const float* __restrict__ dt_bias,
    const float* __restrict__ A_logs, float* __restrict__ dt_arr,
    float* __restrict__ ac_arr, float* __restrict__ cdecay)
{
    __shared__ float sbuf[256];
    int g = blockIdx.x >> 4, c = blockIdx.x & 15;
    int t = threadIdx.x;
    int s = c * 256 + t;
    for (int ht = 0; ht < 24; ++ht) {
        int k = ht / 6, h = ht % 6;
        int l = map_l(s, k);
        float raw = bct[((size_t)g * LL + l) * BSTR + 256 + h] + dt_bias[ht];
        float dtv = raw > 20.f ? raw : log1pf(__expf(raw));
        float dA = dtv * (-__expf(A_logs[ht]));
        sbuf[t] = dA;
        __syncthreads();
        for (int off = 1; off < 256; off <<= 1) {
            float add = (t >= off) ? sbuf[t - off] : 0.f;
            __syncthreads();
            sbuf[t] += add;
            __syncthreads();
        }
        float cum = sbuf[t];
        size_t base = ((size_t)g * 24 + ht) * LL + s;
        dt_arr[base] = dtv;
        ac_arr[base] = cum;
        if (t == 255) cdecay[(g * 24 + ht) * 16 + c] = __expf(cum);
        __syncthreads();
    }
}

// ---------------- MFMA CB: CB[gc][i][j] = sum_n C[i,n]*B[j,n] (bf16 out) ----------------
__global__ __launch_bounds__(256) void cb_k(const float* __restrict__ bct,
                                            __hip_bfloat16* __restrict__ CBm)
{
    int bid = blockIdx.x;                 // gc*4 + jq, 256 blocks
    int jq = bid & 3;
    int gc = bid >> 2;
    int c = gc & 15, g = gc >> 4;
    int t = threadIdx.x;
    int w = t >> 6, lane = t & 63;
    int lr = lane & 15, kq = lane >> 4;
    const float* bg = bct + (size_t)g * LL * BSTR;
    f32x4 acc[4][4] = {};
    for (int ks = 0; ks < 16; ++ks) {
        int n0 = ks * 32 + kq * 8;
        int kd = n0 >> 7, nn = n0 & 127;
        bf16x8 bf[4];
        #pragma unroll
        for (int jt = 0; jt < 4; ++jt) {
            int j = jq * 64 + jt * 16 + lr;
            int l = map_l(c * 256 + j, kd);
            const float* p = bg + (size_t)l * BSTR + nn;
            bf[jt] = pack8(*(const float4*)p, *(const float4*)(p + 4));
        }
        #pragma unroll
        for (int iq = 0; iq < 4; ++iq) {
            int i = (w * 4 + iq) * 16 + lr;
            int l = map_l(c * 256 + i, kd);
            const float* p = bg + (size_t)l * BSTR + 128 + nn;
            bf16x8 af = pack8(*(const float4*)p, *(const float4*)(p + 4));
            #pragma unroll
            for (int jt = 0; jt < 4; ++jt)
                acc[iq][jt] = __builtin_amdgcn_mfma_f32_16x16x32_bf16(af, bf[jt], acc[iq][jt], 0, 0, 0);
        }
    }
    __hip_bfloat16* ob = CBm + (size_t)gc * 65536;
    #pragma unroll
    for (int iq = 0; iq < 4; ++iq)
        #pragma unroll
        for (int jt = 0; jt < 4; ++jt)
            #pragma unroll
            for (int r = 0; r < 4; ++r) {
                int i = (w * 4 + iq) * 16 + kq * 4 + r;
                int j = jq * 64 + jt * 16 + lr;
                ob[(size_t)i * 256 + j] = __float2bfloat16(acc[iq][jt][r]);
            }
}

// ---------------- MFMA states: S[p,n] = sum_j w_j x[j,p] B[j,n] ----------------
__global__ __launch_bounds__(256) void states_k(
    const __hip_bfloat16* __restrict__ XtG, const __hip_bfloat16* __restrict__ Bt,
    const float* __restrict__ dt_arr, const float* __restrict__ ac_arr,
    __hip_bfloat16* __restrict__ states)
{
    __shared__ float wsh[256];
    int bid = blockIdx.x;
    int ht = bid % 24;
    int gc = bid / 24;
    int c = gc & 15, g = gc >> 4;
    int kd = ht / 6;
    int c0 = (ht % 6) * 64;
    int t = threadIdx.x;
    int w = t >> 6, lane = t & 63;
    int lr = lane & 15, kq = lane >> 4;
    const float* dtp = dt_arr + ((size_t)g * 24 + ht) * LL + c * 256;
    const float* acp = ac_arr + ((size_t)g * 24 + ht) * LL + c * 256;
    float ac_last = acp[255];
    wsh[t] = __expf(ac_last - acp[t]) * dtp[t];
    __syncthreads();
    const __hip_bfloat16* xg = XtG + ((size_t)(g * 4 + kd) * 384 + c0) * 4096;
    const __hip_bfloat16* btg = Bt + (size_t)g * 512 * 4096;
    f32x4 acc[4][8] = {};
    for (int ks = 0; ks < 8; ++ks) {
        int j0 = ks * 32 + kq * 8;
        bf16x8 af[4];
        #pragma unroll
        for (int pt = 0; pt < 4; ++pt) {
            bf16x8 xv = *(const bf16x8*)(xg + (size_t)(pt * 16 + lr) * 4096 + c * 256 + j0);
            #pragma unroll
            for (int e = 0; e < 8; ++e) af[pt][e] = f2bf(bf2f(xv[e]) * wsh[j0 + e]);
        }
        #pragma unroll
        for (int nt = 0; nt < 8; ++nt) {
            int n = (w * 8 + nt) * 16 + lr;
            bf16x8 bv = *(const bf16x8*)(btg + (size_t)n * 4096 + c * 256 + j0);
            #pragma unroll
            for (int pt = 0; pt < 4; ++pt)
                acc[pt][nt] = __builtin_amdgcn_mfma_f32_16x16x32_bf16(af[pt], bv, acc[pt][nt], 0, 0, 0);
        }
    }
    __hip_bfloat16* ob = states + ((size_t)gc * 24 + ht) * 32768;
    #pragma unroll
    for (int pt = 0; pt < 4; ++pt)
        #pragma unroll
        for (int nt = 0; nt < 8; ++nt)
            #pragma unroll
            for (int r = 0; r < 4; ++r) {
                int p = pt * 16 + kq * 4 + r;
                int n = (w * 8 + nt) * 16 + lr;
                ob[(size_t)p * 512 + n] = __float2bfloat16(acc[pt][nt][r]);
            }
}

// ---------------- inter-chunk scan, in place ----------------
__global__ void scan_k(__hip_bfloat16* __restrict__ states, const float* __restrict__ cdecay)
{
    int idx = blockIdx.x * 256 + threadIdx.x;
    int g = idx / 786432;
    int r = idx - g * 786432;
    int ht = r >> 15;
    int pn = r & 32767;
    const float* cd = cdecay + (g * 24 + ht) * 16;
    __hip_bfloat16* base = states + ((size_t)g * 384 + ht) * 32768 + pn;
    float S = 0.f;
    #pragma unroll
    for (int c2 = 0; c2 < 16; ++c2) {
        __hip_bfloat16* p = base + (size_t)c2 * 786432;
        float tmp = __bfloat162float(*p);
        *p = __float2bfloat16(S);
        S = S * cd[c2] + tmp;
    }
}

// ---------------- MFMA y: (L∘CB∘dt)·x + exp(ac)·C·prev^T + Ds·x -> atomic ym ----------------
__global__ __launch_bounds__(256) void yk(
    const __hip_bfloat16* __restrict__ XtG, const float* __restrict__ bct,
    const __hip_bfloat16* __restrict__ CBm, const __hip_bfloat16* __restrict__ prev,
    const float* __restrict__ dt_arr, const float* __restrict__ ac_arr,
    const float* __restrict__ Ds, float* __restrict__ ym)
{
    __shared__ float acs[256], dts[256];
    int bid = blockIdx.x;
    int ht = bid % 24;
    int gc = bid / 24;
    int c = gc & 15, g = gc >> 4;
    int kd = ht / 6;
    int c0 = (ht % 6) * 64;
    int t = threadIdx.x;
    int w = t >> 6, lane = t & 63;
    int lr = lane & 15, kq = lane >> 4;
    acs[t] = ac_arr[((size_t)g * 24 + ht) * LL + c * 256 + t];
    dts[t] = dt_arr[((size_t)g * 24 + ht) * LL + c * 256 + t];
    __syncthreads();
    const __hip_bfloat16* xg = XtG + ((size_t)(g * 4 + kd) * 384 + c0) * 4096;
    const __hip_bfloat16* cbb = CBm + (size_t)gc * 65536;
    const float* bg = bct + (size_t)g * LL * BSTR;
    float aci_q[4];
    #pragma unroll
    for (int q = 0; q < 4; ++q) aci_q[q] = acs[(w + 4 * q) * 16 + lr];
    f32x4 acc[4][4] = {};
    // ---- term1: causal M @ x ----
    for (int ks = 0; ks < 8; ++ks) {
        int j0 = ks * 32 + kq * 8;
        float ac_j[8], dt_j[8];
        #pragma unroll
        for (int e = 0; e < 8; ++e) { ac_j[e] = acs[j0 + e]; dt_j[e] = dts[j0 + e]; }
        bf16x8 xb[4];
        #pragma unroll
        for (int pt = 0; pt < 4; ++pt)
            xb[pt] = *(const bf16x8*)(xg + (size_t)(pt * 16 + lr) * 4096 + c * 256 + j0);
        #pragma unroll
        for (int q = 0; q < 4; ++q) {
            int rt = w + 4 * q;
            if (ks * 32 > rt * 16 + 15) continue;        // whole j-block above diagonal
            int i = rt * 16 + lr;
            bf16x8 cb8 = *(const bf16x8*)(cbb + (size_t)i * 256 + j0);
            bf16x8 af;
            #pragma unroll
            for (int e = 0; e < 8; ++e) {
                int j = j0 + e;
                float d = (j <= i) ? (aci_q[q] - ac_j[e]) : -100.f;
                af[e] = f2bf(__expf(d) * dt_j[e] * bf2f(cb8[e]));
            }
            #pragma unroll
            for (int pt = 0; pt < 4; ++pt)
                acc[q][pt] = __builtin_amdgcn_mfma_f32_16x16x32_bf16(af, xb[pt], acc[q][pt], 0, 0, 0);
        }
    }
    // ---- term2: exp(ac_i) C @ prev^T ----
    const __hip_bfloat16* pv = prev + ((size_t)gc * 24 + ht) * 32768;
    float ei_q[4];
    #pragma unroll
    for (int q = 0; q < 4; ++q) ei_q[q] = __expf(aci_q[q]);
    for (int ns = 0; ns < 16; ++ns) {
        int n0 = ns * 32 + kq * 8;
        int kd2 = n0 >> 7, nn = n0 & 127;
        bf16x8 pb[4];
        #pragma unroll
        for (int pt = 0; pt < 4; ++pt)
            pb[pt] = *(const bf16x8*)(pv + (size_t)(pt * 16 + lr) * 512 + n0);
        #pragma unroll
        for (int q = 0; q < 4; ++q) {
            int i = (w + 4 * q) * 16 + lr;
            int l = map_l(c * 256 + i, kd2);
            const float* p = bg + (size_t)l * BSTR + 128 + nn;
            bf16x8 af = pack8s(*(const float4*)p, *(const float4*)(p + 4), ei_q[q]);
            #pragma unroll
            for (int pt = 0; pt < 4; ++pt)
                acc[q][pt] = __builtin_amdgcn_mfma_f32_16x16x32_bf16(af, pb[pt], acc[q][pt], 0, 0, 0);
        }
    }
    // ---- epilogue: + Ds*x, atomic scatter into merged ym ----
    float Dsv = Ds[ht];
    #pragma unroll
    for (int q = 0; q < 4; ++q) {
        int rt = w + 4 * q;
        #pragma unroll
        for (int pt = 0; pt < 4; ++pt) {
            int p = pt * 16 + lr;
            int ibase = rt * 16 + kq * 4;
            bf16x4v x4 = *(const bf16x4v*)(xg + (size_t)p * 4096 + c * 256 + ibase);
            #pragma unroll
            for (int r = 0; r < 4; ++r) {
                int i = ibase + r;
                int l = map_l(c * 256 + i, kd);
                float v = acc[q][pt][r] + Dsv * bf2f(x4[r]);
                atomicAdd(&ym[((size_t)g * LL + l) * 384 + c0 + p], v);
            }
        }
    }
}

// ---------------- gate + RMSNorm (ym already direction-merged) ----------------
__global__ __launch_bounds__(128) void gate_k(
    const float* __restrict__ ym, const __hip_bfloat16* __restrict__ z_silu,
    const float* __restrict__ norm_w, float* __restrict__ gn)
{
    int g = blockIdx.x >> 12;
    int l = blockIdx.x & 4095;
    int t = threadIdx.x;
    size_t base = ((size_t)g * LL + l) * 384;
    float gc[3]; float ssq = 0.f;
    #pragma unroll
    for (int q = 0; q < 3; ++q) {
        int cdim = t + 128 * q;
        float v = ym[base + cdim] * __bfloat162float(z_silu[base + cdim]);
        gc[q] = v;
        ssq += v * v;
    }
    float v = ssq;
    #pragma unroll
    for (int off = 32; off > 0; off >>= 1) v += __shfl_down(v, off);
    __shared__ float tot[2];
    if ((t & 63) == 0) tot[t >> 6] = v;
    __syncthreads();
    float rs = rsqrtf((tot[0] + tot[1]) * (1.f / 384.f) + 1e-5f);
    #pragma unroll
    for (int q = 0; q < 3; ++q) {
        int cdim = t + 128 * q;
        gn[base + cdim] = gc[q] * rs * norm_w[cdim];
    }
}

extern "C" void kernel_launch(void* const* d_in, const int* in_sizes, int n_in,
                              void* d_out, int out_size, void* d_ws, size_t ws_size,
                              hipStream_t stream)
{
    const float* u1      = (const float*)d_in[0];
    const float* u2      = (const float*)d_in[1];
    const float* u21     = (const float*)d_in[2];
    const float* u12     = (const float*)d_in[3];
    const float* W_skip  = (const float*)d_in[4];
    const float* W_xs    = (const float*)d_in[5];
    const float* W_bcdt  = (const float*)d_in[6];
    const float* cxw     = (const float*)d_in[7];
    const float* cxb     = (const float*)d_in[8];
    const float* cbw     = (const float*)d_in[9];
    const float* cbb     = (const float*)d_in[10];
    const float* dt_bias = (const float*)d_in[11];
    const float* A_logs  = (const float*)d_in[12];
    const float* Ds      = (const float*)d_in[13];
    const float* norm_w  = (const float*)d_in[14];
    const float* W_out   = (const float*)d_in[15];
    float* out = (float*)d_out;

    char* w = (char*)d_ws;
    // static layout (bytes)
    size_t o_states = 0;                      // 100,663,296 (bf16 states; early: pre_bc@+0, xs_t@+17.3M; late: gn@+0)
    size_t o_ym  = o_states + 100663296;      // 25,165,824 f32 merged y (early: pre_xs)
    size_t o_xtg = o_ym  + 25165824;          // 50,331,648 bf16 XtG
    size_t o_z   = o_xtg + 50331648;          // 12,582,912 bf16 z_silu
    size_t o_bct = o_z   + 12582912;          // 17,301,504 f32 bct padded
    size_t o_cbm = o_bct + 17301504;          //  8,388,608 bf16 CBm
    size_t o_bt  = o_cbm + 8388608;           // 16,777,216 bf16 Bt
    size_t o_dt  = o_bt  + 16777216;          //  1,572,864 f32 dt_arr
    size_t o_ac  = o_dt  + 1572864;           //  1,572,864 f32 ac_arr
    size_t o_cd  = o_ac  + 1572864;           //      8,192 f32 cdecay
    size_t total = o_cd  + 8192;              // 234,364,928 B
    if (total > ws_size) {
        sentinel_k<<<1, 1, 0, stream>>>(out); // absmax ~1e30 => workspace too small
        return;
    }
    __hip_bfloat16* states = (__hip_bfloat16*)(w + o_states);
    float*          ym     = (float*)(w + o_ym);
    __hip_bfloat16* XtG    = (__hip_bfloat16*)(w + o_xtg);
    __hip_bfloat16* z_silu = (__hip_bfloat16*)(w + o_z);
    float*          bct    = (float*)(w + o_bct);
    __hip_bfloat16* CBm    = (__hip_bfloat16*)(w + o_cbm);
    __hip_bfloat16* Bt     = (__hip_bfloat16*)(w + o_bt);
    float*          dt_arr = (float*)(w + o_dt);
    float*          ac_arr = (float*)(w + o_ac);
    float*          cdecay = (float*)(w + o_cd);
    // transient aliases
    float* pre_xs = (float*)(w + o_ym);              // dead after dwconv_xs
    float* pre_bc = (float*)(w + o_states);          // dead after dwconv_bc
    float* xs_t   = (float*)(w + o_states + 17301504); // dead after xt_k
    float* gn     = (float*)(w + o_states);          // written by gate (states dead)

    dim3 blk(256);
    // 1. input GEMMs
    gemm_k<1, __hip_bfloat16><<<dim3(6, 256), blk, 0, stream>>>(u1, u2, W_skip, z_silu, 384, 192);
    gemm_k<0, float><<<dim3(6, 256), blk, 0, stream>>>(u1, u2, W_xs, pre_xs, 384, 192);
    gemm_k<0, float><<<dim3(5, 256), blk, 0, stream>>>(u21, u12, W_bcdt, pre_bc, CBC, 192);
    // 2. depthwise conv + silu
    dwconv_k<<<dim3((GG * LL * 384) / 256), blk, 0, stream>>>(pre_xs, cxw, cxb, xs_t, 384, 384);
    dwconv_k<<<dim3((GG * LL * CBC + 255) / 256), blk, 0, stream>>>(pre_bc, cbw, cbb, bct, CBC, BSTR);
    // 3. zero merged-y accumulator (pre_xs now dead)
    hipMemsetAsync(ym, 0, (size_t)GG * LL * 384 * 4, stream);
    // 4. transposed/gathered bf16 operand tensors
    xt_k<<<dim3(1536), blk, 0, stream>>>(xs_t, XtG);
    bt_k<<<dim3(2048), blk, 0, stream>>>(bct, Bt);
    // 5. dt softplus + per-chunk cumsum
    dtscan_k<<<dim3(64), blk, 0, stream>>>(bct, dt_bias, A_logs, dt_arr, ac_arr, cdecay);
    // 6. CB = C·B^T (MFMA)
    cb_k<<<dim3(256), blk, 0, stream>>>(bct, CBm);
    // 7. per-chunk states (MFMA)
    states_k<<<dim3(1536), blk, 0, stream>>>(XtG, Bt, dt_arr, ac_arr, states);
    // 8. inter-chunk scan
    scan_k<<<dim3(12288), blk, 0, stream>>>(states, cdecay);
    // 9. y (MFMA) -> atomic merged ym
    yk<<<dim3(1536), blk, 0, stream>>>(XtG, bct, CBm, states, dt_arr, ac_arr, Ds, ym);
    // 10. gate + RMSNorm
    gate_k<<<dim3(16384), dim3(128), 0, stream>>>(ym, z_silu, norm_w, gn);
    // 11. output GEMM
    gemm_k<0, float><<<dim3(3, 256), blk, 0, stream>>>(gn, gn + (size_t)8192 * 384, W_out, out, 192, 384);
}

// Round 4
// 632.886 us; speedup vs baseline: 2.5817x; 1.2331x over previous
//
#include <hip/hip_runtime.h>
#include <hip/hip_bf16.h>

#define DEV __device__ __forceinline__

static constexpr int LL   = 4096;   // 64x64
static constexpr int GG   = 4;      // 2 branches x 2 batch
static constexpr int CBC  = 262;    // 2*128 + 6
static constexpr int BSTR = 264;    // padded bct row stride (floats), 16B-aligned

typedef float f32x4  __attribute__((ext_vector_type(4)));
typedef short bf16x8 __attribute__((ext_vector_type(8)));
typedef short bf16x4v __attribute__((ext_vector_type(4)));

DEV int map_l(int s, int k) {
    int m = (k & 2) ? (4095 - s) : s;
    if (k & 1) m = ((m & 63) << 6) | (m >> 6);
    return m;
}
DEV float silu_f(float x) { return x / (1.f + __expf(-x)); }
DEV short f2bf(float f) {
    union { __hip_bfloat16 h; short s; } u;
    u.h = __float2bfloat16(f);
    return u.s;
}
DEV float bf2f(short s) {
    return __uint_as_float(((unsigned)(unsigned short)s) << 16);
}
DEV bf16x8 pack8(float4 a, float4 b) {
    bf16x8 r;
    r[0]=f2bf(a.x); r[1]=f2bf(a.y); r[2]=f2bf(a.z); r[3]=f2bf(a.w);
    r[4]=f2bf(b.x); r[5]=f2bf(b.y); r[6]=f2bf(b.z); r[7]=f2bf(b.w);
    return r;
}
// 8-B-aligned bf16x8 load (two dwordx2) for reversed-direction bases
DEV bf16x8 load8u(const __hip_bfloat16* p) {
    bf16x4v lo = *(const bf16x4v*)p;
    bf16x4v hi = *(const bf16x4v*)(p + 4);
    bf16x8 r;
    r[0]=lo[0]; r[1]=lo[1]; r[2]=lo[2]; r[3]=lo[3];
    r[4]=hi[0]; r[5]=hi[1]; r[6]=hi[2]; r[7]=hi[3];
    return r;
}
DEV void store16(__hip_bfloat16* p, const float* v) {
    bf16x8 a, b;
    #pragma unroll
    for (int e = 0; e < 8; ++e) { a[e] = f2bf(v[e]); b[e] = f2bf(v[8+e]); }
    *(bf16x8*)p = a;
    *((bf16x8*)p + 1) = b;
}
DEV void storeT(float v, float* p) { *p = v; }
DEV void storeT(float v, __hip_bfloat16* p) { *p = __float2bfloat16(v); }

__global__ void sentinel_k(float* out) { out[0] = 1e30f; }

// ---------------- weight transpose: W[K][N] -> Wt[Npad][K] bf16 (pad rows zero) ----------------
__global__ void wt_k(const float* __restrict__ W, __hip_bfloat16* __restrict__ Wt,
                     int K, int N, int Npad)
{
    int idx = blockIdx.x * 256 + threadIdx.x;
    if (idx >= Npad * K) return;
    int n = idx / K, k = idx - n * K;
    Wt[idx] = __float2bfloat16((n < N) ? W[(size_t)k * N + n] : 0.f);
}

// ---------------- MFMA GEMM: C[M x N] = act(A * W), A f32 row-major (A0 rows<8192, A1 rest),
// W given transposed bf16 Wt[Npad][K]. Tile 128x64, 4 waves. ----------------
template<int ACT, typename OutT>
__global__ __launch_bounds__(256) void mgemm_k(
    const float* __restrict__ A0, const float* __restrict__ A1,
    const __hip_bfloat16* __restrict__ Wt, OutT* __restrict__ C,
    int N, int Kd)
{
    int i0 = blockIdx.y * 128;
    int j0 = blockIdx.x * 64;
    int t = threadIdx.x;
    int w = t >> 6, lane = t & 63;
    int lr = lane & 15, kq = lane >> 4;
    const float* arow[2];
    #pragma unroll
    for (int a = 0; a < 2; ++a) {
        int grow = i0 + w * 32 + a * 16 + lr;
        const float* Ap = (grow < 8192) ? A0 : A1;
        arow[a] = Ap + (size_t)(grow & 8191) * Kd;
    }
    f32x4 acc[2][4] = {};
    for (int k0 = 0; k0 < Kd; k0 += 32) {
        int kb = k0 + kq * 8;
        bf16x8 af[2];
        #pragma unroll
        for (int a = 0; a < 2; ++a)
            af[a] = pack8(*(const float4*)(arow[a] + kb), *(const float4*)(arow[a] + kb + 4));
        #pragma unroll
        for (int b = 0; b < 4; ++b) {
            int n = j0 + b * 16 + lr;
            bf16x8 bfr = *(const bf16x8*)(Wt + (size_t)n * Kd + kb);
            #pragma unroll
            for (int a = 0; a < 2; ++a)
                acc[a][b] = __builtin_amdgcn_mfma_f32_16x16x32_bf16(af[a], bfr, acc[a][b], 0, 0, 0);
        }
    }
    #pragma unroll
    for (int a = 0; a < 2; ++a)
        #pragma unroll
        for (int b = 0; b < 4; ++b)
            #pragma unroll
            for (int r = 0; r < 4; ++r) {
                int row = i0 + w * 32 + a * 16 + kq * 4 + r;
                int col = j0 + b * 16 + lr;
                if (col < N) {
                    float v = acc[a][b][r];
                    if (ACT) v = silu_f(v);
                    storeT(v, &C[(size_t)row * N + col]);
                }
            }
}

// ---------------- depthwise 3x3 conv (pad 1) + bias + silu ----------------
__global__ void dwconv_k(const float* __restrict__ in, const float* __restrict__ w,
                         const float* __restrict__ bias, float* __restrict__ out,
                         int Cin, int Cout)
{
    int idx = blockIdx.x * 256 + threadIdx.x;
    int total = GG * LL * Cin;
    if (idx >= total) return;
    int c = idx % Cin;
    int l = (idx / Cin) % LL;
    int g = idx / (Cin * LL);
    int h = l >> 6, ww = l & 63;
    float acc = bias[c];
    #pragma unroll
    for (int dy = 0; dy < 3; ++dy) {
        int hh = h + dy - 1;
        if ((unsigned)hh >= 64u) continue;
        #pragma unroll
        for (int dx = 0; dx < 3; ++dx) {
            int wx = ww + dx - 1;
            if ((unsigned)wx >= 64u) continue;
            acc += in[((size_t)g * LL + (hh << 6) + wx) * Cin + c] * w[c * 9 + dy * 3 + dx];
        }
    }
    out[((size_t)g * LL + l) * Cout + c] = silu_f(acc);
}

// ---------------- xs transpose/gather: XtG[g][kd01][pc 384][s 4096] bf16 (2 dirs only) ----------------
__global__ __launch_bounds__(256) void xt_k(const float* __restrict__ xs_t,
                                            __hip_bfloat16* __restrict__ XtG)
{
    __shared__ float ls[16][17][17];
    int bid = blockIdx.x;                 // 24 pct x 4 wt x 4 ht x 4 g = 1536
    int pct = bid % 24;
    int rest = bid / 24;
    int wt = rest & 3, ht2 = (rest >> 2) & 3, g = rest >> 4;
    int h0 = ht2 * 16, w0 = wt * 16, pc0 = pct * 16;
    int t = threadIdx.x;
    int pcl = t & 15, hwb = t >> 4;
    #pragma unroll
    for (int r = 0; r < 16; ++r) {
        int hw = hwb + r * 16;
        int h = hw >> 4, w2 = hw & 15;
        ls[h][w2][pcl] = xs_t[((size_t)g * LL + (h0 + h) * 64 + (w0 + w2)) * 384 + pc0 + pcl];
    }
    __syncthreads();
    int pc = t >> 4, q = t & 15;
    float v[16];
    size_t rowbase;
    // kd0: s = (h0+q)*64 + w0 + e
    #pragma unroll
    for (int e = 0; e < 16; ++e) v[e] = ls[q][e][pc];
    rowbase = ((size_t)(g * 2 + 0) * 384 + pc0 + pc) * 4096;
    store16(XtG + rowbase + (h0 + q) * 64 + w0, v);
    // kd1: s = (w0+q)*64 + h0 + e
    #pragma unroll
    for (int e = 0; e < 16; ++e) v[e] = ls[e][q][pc];
    rowbase = ((size_t)(g * 2 + 1) * 384 + pc0 + pc) * 4096;
    store16(XtG + rowbase + (w0 + q) * 64 + h0, v);
}

// ---------------- B transpose/gather: Bt[g][n 512][s 4096] bf16 (all 4 dirs) ----------------
__global__ __launch_bounds__(256) void bt_k(const float* __restrict__ bct,
                                            __hip_bfloat16* __restrict__ Bt)
{
    __shared__ float ls[16][17][17];
    int bid = blockIdx.x;                 // 32 nt x 4 wt x 4 ht x 4 g = 2048
    int nt = bid & 31;
    int rest = bid >> 5;
    int wt = rest & 3, ht2 = (rest >> 2) & 3, g = rest >> 4;
    int h0 = ht2 * 16, w0 = wt * 16;
    int kd = nt >> 3, ch0 = (nt & 7) * 16;
    int t = threadIdx.x;
    int cl = t & 15, hwb = t >> 4;
    #pragma unroll
    for (int r = 0; r < 16; ++r) {
        int hw = hwb + r * 16;
        int h = hw >> 4, w2 = hw & 15;
        ls[h][w2][cl] = bct[((size_t)g * LL + (h0 + h) * 64 + (w0 + w2)) * BSTR + ch0 + cl];
    }
    __syncthreads();
    int pc = t >> 4, q = t & 15;
    int n = nt * 16 + pc;
    __hip_bfloat16* rowp = Bt + ((size_t)g * 512 + n) * 4096;
    float v[16];
    if (kd == 0) {
        #pragma unroll
        for (int e = 0; e < 16; ++e) v[e] = ls[q][e][pc];
        store16(rowp + (h0 + q) * 64 + w0, v);
    } else if (kd == 1) {
        #pragma unroll
        for (int e = 0; e < 16; ++e) v[e] = ls[e][q][pc];
        store16(rowp + (w0 + q) * 64 + h0, v);
    } else if (kd == 2) {
        #pragma unroll
        for (int e = 0; e < 16; ++e) v[e] = ls[q][15 - e][pc];
        store16(rowp + 4095 - (h0 + q) * 64 - w0 - 15, v);
    } else {
        #pragma unroll
        for (int e = 0; e < 16; ++e) v[e] = ls[15 - e][q][pc];
        store16(rowp + 4095 - (w0 + q) * 64 - h0 - 15, v);
    }
}

// ---------------- C_scan[g][s 4096][n 256] bf16 (kd0/kd1 C-channels; kd2/3 read row 4095-s) ----------------
__global__ __launch_bounds__(256) void cs_k(const float* __restrict__ bct,
                                            __hip_bfloat16* __restrict__ Cs)
{
    __shared__ float ls[16][16][17];
    int bid = blockIdx.x;                 // 16 ct x 4 wt x 4 ht x 4 g = 1024
    int ct = bid & 15;
    int rest = bid >> 4;
    int wt = rest & 3, ht2 = (rest >> 2) & 3, g = rest >> 4;
    int h0 = ht2 * 16, w0 = wt * 16;
    int kd = ct >> 3, ch0 = (ct & 7) * 16;   // C channels at bct offset 128+ch0
    int t = threadIdx.x;
    int cl = t & 15, hwb = t >> 4;
    #pragma unroll
    for (int r = 0; r < 16; ++r) {
        int hw = hwb + r * 16;
        int h = hw >> 4, w2 = hw & 15;
        ls[h][w2][cl] = bct[((size_t)g * LL + (h0 + h) * 64 + (w0 + w2)) * BSTR + 128 + ch0 + cl];
    }
    __syncthreads();
    int h = t >> 4, w2 = t & 15;
    int s = (kd == 0) ? (h0 + h) * 64 + (w0 + w2) : (w0 + w2) * 64 + (h0 + h);
    float v[16];
    #pragma unroll
    for (int e = 0; e < 16; ++e) v[e] = ls[h][w2][e];
    store16(Cs + ((size_t)g * 4096 + s) * 256 + kd * 128 + ch0, v);
}

// ---------------- dt softplus + per-chunk inclusive cumsum of dt*A (shuffle scan) ----------------
__global__ __launch_bounds__(256) void dtscan_k(
    const float* __restrict__ bct, const float* __restrict__ dt_bias,
    const float* __restrict__ A_logs, float* __restrict__ dt_arr,
    float* __restrict__ ac_arr, float* __restrict__ cdecay)
{
    int bid = blockIdx.x;                 // ht + 24*(c + 16*g) = 1536
    int ht = bid % 24;
    int gc = bid / 24;
    int c = gc & 15, g = gc >> 4;
    int k = ht / 6, h = ht % 6;
    int t = threadIdx.x;
    int s = c * 256 + t;
    int l = map_l(s, k);
    float raw = bct[((size_t)g * LL + l) * BSTR + 256 + h] + dt_bias[ht];
    float dtv = raw > 20.f ? raw : log1pf(__expf(raw));
    float dA = dtv * (-__expf(A_logs[ht]));
    float v = dA;
    #pragma unroll
    for (int off = 1; off < 64; off <<= 1) {
        float u = __shfl_up(v, off);
        if ((t & 63) >= off) v += u;
    }
    __shared__ float wsum[4];
    if ((t & 63) == 63) wsum[t >> 6] = v;
    __syncthreads();
    float add = 0.f;
    #pragma unroll
    for (int w2 = 0; w2 < 3; ++w2)
        if (w2 < (t >> 6)) add += wsum[w2];
    float cum = v + add;
    size_t base = ((size_t)g * 24 + ht) * LL + s;
    dt_arr[base] = dtv;
    ac_arr[base] = cum;
    if (t == 255) cdecay[(g * 24 + ht) * 16 + c] = __expf(cum);
}

// ---------------- MFMA CB: CB[gc][i][j] = sum_n C[i,n]*B[j,n] (bf16 out) ----------------
__global__ __launch_bounds__(256) void cb_k(const float* __restrict__ bct,
                                            const __hip_bfloat16* __restrict__ Cs,
                                            __hip_bfloat16* __restrict__ CBm)
{
    int bid = blockIdx.x;                 // gc*4 + jq, 256 blocks
    int jq = bid & 3;
    int gc = bid >> 2;
    int c = gc & 15, g = gc >> 4;
    int t = threadIdx.x;
    int w = t >> 6, lane = t & 63;
    int lr = lane & 15, kq = lane >> 4;
    const float* bg = bct + (size_t)g * LL * BSTR;
    const __hip_bfloat16* cg = Cs + (size_t)g * 4096 * 256;
    f32x4 acc[4][4] = {};
    for (int ks = 0; ks < 16; ++ks) {
        int n0 = ks * 32 + kq * 8;
        int kd = n0 >> 7, nn = n0 & 127;
        bf16x8 bfr[4];
        #pragma unroll
        for (int jt = 0; jt < 4; ++jt) {
            int j = jq * 64 + jt * 16 + lr;
            int l = map_l(c * 256 + j, kd);
            const float* p = bg + (size_t)l * BSTR + nn;
            bfr[jt] = pack8(*(const float4*)p, *(const float4*)(p + 4));
        }
        #pragma unroll
        for (int iq = 0; iq < 4; ++iq) {
            int i = (w * 4 + iq) * 16 + lr;
            int s = c * 256 + i;
            int row = (kd < 2) ? s : 4095 - s;
            int col = ((kd & 1) << 7) + nn;
            bf16x8 af = *(const bf16x8*)(cg + (size_t)row * 256 + col);
            #pragma unroll
            for (int jt = 0; jt < 4; ++jt)
                acc[iq][jt] = __builtin_amdgcn_mfma_f32_16x16x32_bf16(af, bfr[jt], acc[iq][jt], 0, 0, 0);
        }
    }
    __hip_bfloat16* ob = CBm + (size_t)gc * 65536;
    #pragma unroll
    for (int iq = 0; iq < 4; ++iq)
        #pragma unroll
        for (int jt = 0; jt < 4; ++jt)
            #pragma unroll
            for (int r = 0; r < 4; ++r) {
                int i = (w * 4 + iq) * 16 + kq * 4 + r;
                int j = jq * 64 + jt * 16 + lr;
                ob[(size_t)i * 256 + j] = __float2bfloat16(acc[iq][jt][r]);
            }
}

// ---------------- MFMA states: S[p,n] = sum_j w_j x[j,p] B[j,n] ----------------
__global__ __launch_bounds__(256) void states_k(
    const __hip_bfloat16* __restrict__ XtG, const __hip_bfloat16* __restrict__ Bt,
    const float* __restrict__ dt_arr, const float* __restrict__ ac_arr,
    __hip_bfloat16* __restrict__ states)
{
    __shared__ float wsh[256];
    // XCD swizzle (perf heuristic only): group all 24 ht of one gc on one XCD
    int task = (blockIdx.x & 7) * 192 + (blockIdx.x >> 3);
    int ht = task % 24;
    int gc = task / 24;
    int c = gc & 15, g = gc >> 4;
    int kd = ht / 6;
    bool rev = kd >= 2;
    int c0 = (ht % 6) * 64;
    int t = threadIdx.x;
    int w = t >> 6, lane = t & 63;
    int lr = lane & 15, kq = lane >> 4;
    const float* dtp = dt_arr + ((size_t)g * 24 + ht) * LL + c * 256;
    const float* acp = ac_arr + ((size_t)g * 24 + ht) * LL + c * 256;
    float ac_last = acp[255];
    wsh[t] = __expf(ac_last - acp[t]) * dtp[t];
    __syncthreads();
    const __hip_bfloat16* xg = XtG + ((size_t)(g * 2 + (kd & 1)) * 384 + c0) * 4096;
    const __hip_bfloat16* btg = Bt + (size_t)g * 512 * 4096;
    f32x4 acc[4][8] = {};
    for (int ks = 0; ks < 8; ++ks) {
        int j0 = ks * 32 + kq * 8;
        bf16x8 af[4];
        #pragma unroll
        for (int pt = 0; pt < 4; ++pt) {
            size_t rowoff = (size_t)(pt * 16 + lr) * 4096;
            if (!rev) {
                bf16x8 xv = *(const bf16x8*)(xg + rowoff + c * 256 + j0);
                #pragma unroll
                for (int e = 0; e < 8; ++e) af[pt][e] = f2bf(bf2f(xv[e]) * wsh[j0 + e]);
            } else {
                bf16x8 xv = load8u(xg + rowoff + 4088 - c * 256 - j0);
                #pragma unroll
                for (int e = 0; e < 8; ++e) af[pt][e] = f2bf(bf2f(xv[7 - e]) * wsh[j0 + e]);
            }
        }
        #pragma unroll
        for (int nt = 0; nt < 8; ++nt) {
            int n = (w * 8 + nt) * 16 + lr;
            bf16x8 bv = *(const bf16x8*)(btg + (size_t)n * 4096 + c * 256 + j0);
            #pragma unroll
            for (int pt = 0; pt < 4; ++pt)
                acc[pt][nt] = __builtin_amdgcn_mfma_f32_16x16x32_bf16(af[pt], bv, acc[pt][nt], 0, 0, 0);
        }
    }
    __hip_bfloat16* ob = states + ((size_t)gc * 24 + ht) * 32768;
    #pragma unroll
    for (int pt = 0; pt < 4; ++pt)
        #pragma unroll
        for (int nt = 0; nt < 8; ++nt)
            #pragma unroll
            for (int r = 0; r < 4; ++r) {
                int p = pt * 16 + kq * 4 + r;
                int n = (w * 8 + nt) * 16 + lr;
                ob[(size_t)p * 512 + n] = __float2bfloat16(acc[pt][nt][r]);
            }
}

// ---------------- inter-chunk scan, in place ----------------
__global__ void scan_k(__hip_bfloat16* __restrict__ states, const float* __restrict__ cdecay)
{
    int idx = blockIdx.x * 256 + threadIdx.x;
    int g = idx / 786432;
    int r = idx - g * 786432;
    int ht = r >> 15;
    int pn = r & 32767;
    const float* cd = cdecay + (g * 24 + ht) * 16;
    __hip_bfloat16* base = states + ((size_t)g * 384 + ht) * 32768 + pn;
    float S = 0.f;
    #pragma unroll
    for (int c2 = 0; c2 < 16; ++c2) {
        __hip_bfloat16* p = base + (size_t)c2 * 786432;
        float tmp = __bfloat162float(*p);
        *p = __float2bfloat16(S);
        S = S * cd[c2] + tmp;
    }
}

// ---------------- MFMA y: exp(ac)*C*prev^T (first), then causal M*x, + Ds*x -> atomic ym ----------------
__global__ __launch_bounds__(256) void yk(
    const __hip_bfloat16* __restrict__ XtG, const __hip_bfloat16* __restrict__ Cs,
    const __hip_bfloat16* __restrict__ CBm, const __hip_bfloat16* __restrict__ prev,
    const float* __restrict__ dt_arr, const float* __restrict__ ac_arr,
    const float* __restrict__ Ds, float* __restrict__ ym)
{
    __shared__ float acs[256], dts[256];
    // XCD swizzle (perf heuristic only)
    int task = (blockIdx.x & 7) * 192 + (blockIdx.x >> 3);
    int ht = task % 24;
    int gc = task / 24;
    int c = gc & 15, g = gc >> 4;
    int kd = ht / 6;
    bool rev = kd >= 2;
    int c0 = (ht % 6) * 64;
    int t = threadIdx.x;
    int w = t >> 6, lane = t & 63;
    int lr = lane & 15, kq = lane >> 4;
    acs[t] = ac_arr[((size_t)g * 24 + ht) * LL + c * 256 + t];
    dts[t] = dt_arr[((size_t)g * 24 + ht) * LL + c * 256 + t];
    __syncthreads();
    const __hip_bfloat16* xg = XtG + ((size_t)(g * 2 + (kd & 1)) * 384 + c0) * 4096;
    const __hip_bfloat16* cbb = CBm + (size_t)gc * 65536;
    const __hip_bfloat16* cg = Cs + (size_t)g * 4096 * 256;
    f32x4 acc[4][4] = {};
    // ---- term2 FIRST (unscaled): C @ prev^T ----
    const __hip_bfloat16* pv = prev + ((size_t)gc * 24 + ht) * 32768;
    for (int ns = 0; ns < 16; ++ns) {
        int n0 = ns * 32 + kq * 8;
        int kd2 = n0 >> 7, nn = n0 & 127;
        int col = ((kd2 & 1) << 7) + nn;
        bf16x8 pb[4];
        #pragma unroll
        for (int pt = 0; pt < 4; ++pt)
            pb[pt] = *(const bf16x8*)(pv + (size_t)(pt * 16 + lr) * 512 + n0);
        #pragma unroll
        for (int q = 0; q < 4; ++q) {
            int i = (w + 4 * q) * 16 + lr;
            int s = c * 256 + i;
            int row = (kd2 < 2) ? s : 4095 - s;
            bf16x8 af = *(const bf16x8*)(cg + (size_t)row * 256 + col);
            #pragma unroll
            for (int pt = 0; pt < 4; ++pt)
                acc[q][pt] = __builtin_amdgcn_mfma_f32_16x16x32_bf16(af, pb[pt], acc[q][pt], 0, 0, 0);
        }
    }
    // ---- scale term2 by exp(ac_i) in place ----
    #pragma unroll
    for (int q = 0; q < 4; ++q)
        #pragma unroll
        for (int r = 0; r < 4; ++r) {
            float er = __expf(acs[(w + 4 * q) * 16 + kq * 4 + r]);
            #pragma unroll
            for (int pt = 0; pt < 4; ++pt) acc[q][pt][r] *= er;
        }
    // ---- term1: causal M @ x accumulates on top ----
    float aci_q[4];
    #pragma unroll
    for (int q = 0; q < 4; ++q) aci_q[q] = acs[(w + 4 * q) * 16 + lr];
    for (int ks = 0; ks < 8; ++ks) {
        int j0 = ks * 32 + kq * 8;
        bf16x8 xb[4];
        #pragma unroll
        for (int pt = 0; pt < 4; ++pt) {
            size_t rowoff = (size_t)(pt * 16 + lr) * 4096;
            xb[pt] = rev ? load8u(xg + rowoff + 4088 - c * 256 - j0)
                         : *(const bf16x8*)(xg + rowoff + c * 256 + j0);
        }
        #pragma unroll
        for (int q = 0; q < 4; ++q) {
            int rt = w + 4 * q;
            if (ks * 32 > rt * 16 + 15) continue;        // whole j-block above diagonal
            int i = rt * 16 + lr;
            bf16x8 cb8 = *(const bf16x8*)(cbb + (size_t)i * 256 + j0);
            bf16x8 af;
            #pragma unroll
            for (int e = 0; e < 8; ++e) {
                int jj = rev ? (j0 + 7 - e) : (j0 + e);   // element e of xb holds j=jj
                float d = (jj <= i) ? (aci_q[q] - acs[jj]) : -100.f;
                af[e] = f2bf(__expf(d) * dts[jj] * bf2f(cb8[jj - j0]));
            }
            #pragma unroll
            for (int pt = 0; pt < 4; ++pt)
                acc[q][pt] = __builtin_amdgcn_mfma_f32_16x16x32_bf16(af, xb[pt], acc[q][pt], 0, 0, 0);
        }
    }
    // ---- epilogue: + Ds*x, atomic scatter into merged ym ----
    float Dsv = Ds[ht];
    #pragma unroll
    for (int q = 0; q < 4; ++q) {
        int rt = w + 4 * q;
        #pragma unroll
        for (int pt = 0; pt < 4; ++pt) {
            int p = pt * 16 + lr;
            int ibase = rt * 16 + kq * 4;
            size_t sa = rev ? (size_t)(4092 - c * 256 - ibase) : (size_t)(c * 256 + ibase);
            bf16x4v x4 = *(const bf16x4v*)(xg + (size_t)p * 4096 + sa);
            #pragma unroll
            for (int r = 0; r < 4; ++r) {
                int i = ibase + r;
                int l = map_l(c * 256 + i, kd);
                float xv = bf2f(x4[rev ? 3 - r : r]);
                float v = acc[q][pt][r] + Dsv * xv;
                atomicAdd(&ym[((size_t)g * LL + l) * 384 + c0 + p], v);
            }
        }
    }
}

// ---------------- gate + RMSNorm (ym already direction-merged) ----------------
__global__ __launch_bounds__(128) void gate_k(
    const float* __restrict__ ym, const __hip_bfloat16* __restrict__ z_silu,
    const float* __restrict__ norm_w, float* __restrict__ gn)
{
    int g = blockIdx.x >> 12;
    int l = blockIdx.x & 4095;
    int t = threadIdx.x;
    size_t base = ((size_t)g * LL + l) * 384;
    float gc[3]; float ssq = 0.f;
    #pragma unroll
    for (int q = 0; q < 3; ++q) {
        int cdim = t + 128 * q;
        float v = ym[base + cdim] * __bfloat162float(z_silu[base + cdim]);
        gc[q] = v;
        ssq += v * v;
    }
    float v = ssq;
    #pragma unroll
    for (int off = 32; off > 0; off >>= 1) v += __shfl_down(v, off);
    __shared__ float tot[2];
    if ((t & 63) == 0) tot[t >> 6] = v;
    __syncthreads();
    float rs = rsqrtf((tot[0] + tot[1]) * (1.f / 384.f) + 1e-5f);
    #pragma unroll
    for (int q = 0; q < 3; ++q) {
        int cdim = t + 128 * q;
        gn[base + cdim] = gc[q] * rs * norm_w[cdim];
    }
}

extern "C" void kernel_launch(void* const* d_in, const int* in_sizes, int n_in,
                              void* d_out, int out_size, void* d_ws, size_t ws_size,
                              hipStream_t stream)
{
    const float* u1      = (const float*)d_in[0];
    const float* u2      = (const float*)d_in[1];
    const float* u21     = (const float*)d_in[2];
    const float* u12     = (const float*)d_in[3];
    const float* W_skip  = (const float*)d_in[4];
    const float* W_xs    = (const float*)d_in[5];
    const float* W_bcdt  = (const float*)d_in[6];
    const float* cxw     = (const float*)d_in[7];
    const float* cxb     = (const float*)d_in[8];
    const float* cbw     = (const float*)d_in[9];
    const float* cbb     = (const float*)d_in[10];
    const float* dt_bias = (const float*)d_in[11];
    const float* A_logs  = (const float*)d_in[12];
    const float* Ds      = (const float*)d_in[13];
    const float* norm_w  = (const float*)d_in[14];
    const float* W_out   = (const float*)d_in[15];
    float* out = (float*)d_out;

    char* w = (char*)d_ws;
    size_t o_states = 0;                      // 100,663,296 bf16 states (early: pre_bc@+0, xs_t@+17.3M; late: gn@+0)
    size_t o_ym  = o_states + 100663296;      // 25,165,824 f32 merged y (early: pre_xs)
    size_t o_xtg = o_ym  + 25165824;          // 25,165,824 bf16 XtG (2 dirs)
    size_t o_z   = o_xtg + 25165824;          // 12,582,912 bf16 z_silu
    size_t o_bct = o_z   + 12582912;          // 17,301,504 f32 bct padded
    size_t o_cbm = o_bct + 17301504;          //  8,388,608 bf16 CBm
    size_t o_bt  = o_cbm + 8388608;           // 16,777,216 bf16 Bt
    size_t o_cs  = o_bt  + 16777216;          //  8,388,608 bf16 C_scan
    size_t o_dt  = o_cs  + 8388608;           //  1,572,864 f32 dt_arr
    size_t o_ac  = o_dt  + 1572864;           //  1,572,864 f32 ac_arr
    size_t o_cd  = o_ac  + 1572864;           //      8,192 f32 cdecay
    size_t o_wt  = o_cd  + 8192;              //    589,824 bf16 Wt x4
    size_t total = o_wt  + 589824;            // = 218,177,536 B (< proven 238.5 MB)
    if (total > ws_size) {
        sentinel_k<<<1, 1, 0, stream>>>(out); // absmax ~1e30 => workspace too small
        return;
    }
    __hip_bfloat16* states = (__hip_bfloat16*)(w + o_states);
    float*          ym     = (float*)(w + o_ym);
    __hip_bfloat16* XtG    = (__hip_bfloat16*)(w + o_xtg);
    __hip_bfloat16* z_silu = (__hip_bfloat16*)(w + o_z);
    float*          bct    = (float*)(w + o_bct);
    __hip_bfloat16* CBm    = (__hip_bfloat16*)(w + o_cbm);
    __hip_bfloat16* Bt     = (__hip_bfloat16*)(w + o_bt);
    __hip_bfloat16* Cs     = (__hip_bfloat16*)(w + o_cs);
    float*          dt_arr = (float*)(w + o_dt);
    float*          ac_arr = (float*)(w + o_ac);
    float*          cdecay = (float*)(w + o_cd);
    __hip_bfloat16* Wt_skip = (__hip_bfloat16*)(w + o_wt);
    __hip_bfloat16* Wt_xs   = Wt_skip + 384 * 192;
    __hip_bfloat16* Wt_bcdt = Wt_xs   + 384 * 192;
    __hip_bfloat16* Wt_out  = Wt_bcdt + 320 * 192;
    // transient aliases
    float* pre_xs = (float*)(w + o_ym);                // dead after dwconv_xs
    float* pre_bc = (float*)(w + o_states);            // dead after dwconv_bc
    float* xs_t   = (float*)(w + o_states + 17301504); // dead after xt_k
    float* gn     = (float*)(w + o_states);            // written by gate (states dead)

    dim3 blk(256);
    // 0. weight transposes (bf16)
    wt_k<<<dim3(288), blk, 0, stream>>>(W_skip, Wt_skip, 192, 384, 384);
    wt_k<<<dim3(288), blk, 0, stream>>>(W_xs,   Wt_xs,   192, 384, 384);
    wt_k<<<dim3(240), blk, 0, stream>>>(W_bcdt, Wt_bcdt, 192, 262, 320);
    wt_k<<<dim3(288), blk, 0, stream>>>(W_out,  Wt_out,  384, 192, 192);
    // 1. input GEMMs (MFMA)
    mgemm_k<1, __hip_bfloat16><<<dim3(6, 128), blk, 0, stream>>>(u1, u2, Wt_skip, z_silu, 384, 192);
    mgemm_k<0, float><<<dim3(6, 128), blk, 0, stream>>>(u1, u2, Wt_xs, pre_xs, 384, 192);
    mgemm_k<0, float><<<dim3(5, 128), blk, 0, stream>>>(u21, u12, Wt_bcdt, pre_bc, CBC, 192);
    // 2. depthwise conv + silu
    dwconv_k<<<dim3((GG * LL * 384) / 256), blk, 0, stream>>>(pre_xs, cxw, cxb, xs_t, 384, 384);
    dwconv_k<<<dim3((GG * LL * CBC + 255) / 256), blk, 0, stream>>>(pre_bc, cbw, cbb, bct, CBC, BSTR);
    // 3. zero merged-y accumulator (pre_xs now dead)
    hipMemsetAsync(ym, 0, (size_t)GG * LL * 384 * 4, stream);
    // 4. transposed/gathered bf16 operand tensors
    xt_k<<<dim3(1536), blk, 0, stream>>>(xs_t, XtG);
    bt_k<<<dim3(2048), blk, 0, stream>>>(bct, Bt);
    cs_k<<<dim3(1024), blk, 0, stream>>>(bct, Cs);
    // 5. dt softplus + per-chunk cumsum
    dtscan_k<<<dim3(1536), blk, 0, stream>>>(bct, dt_bias, A_logs, dt_arr, ac_arr, cdecay);
    // 6. CB = C·B^T (MFMA)
    cb_k<<<dim3(256), blk, 0, stream>>>(bct, Cs, CBm);
    // 7. per-chunk states (MFMA, XCD-swizzled)
    states_k<<<dim3(1536), blk, 0, stream>>>(XtG, Bt, dt_arr, ac_arr, states);
    // 8. inter-chunk scan
    scan_k<<<dim3(12288), blk, 0, stream>>>(states, cdecay);
    // 9. y (MFMA, XCD-swizzled) -> atomic merged ym
    yk<<<dim3(1536), blk, 0, stream>>>(XtG, Cs, CBm, states, dt_arr, ac_arr, Ds, ym);
    // 10. gate + RMSNorm
    gate_k<<<dim3(16384), dim3(128), 0, stream>>>(ym, z_silu, norm_w, gn);
    // 11. output GEMM (MFMA)
    mgemm_k<0, float><<<dim3(3, 128), blk, 0, stream>>>(gn, gn + (size_t)8192 * 384, Wt_out, out, 192, 384);
}

// Round 5
// 589.348 us; speedup vs baseline: 2.7724x; 1.0739x over previous
//
#include <hip/hip_runtime.h>
#include <hip/hip_bf16.h>

#define DEV __device__ __forceinline__

static constexpr int LL   = 4096;   // 64x64
static constexpr int GG   = 4;      // 2 branches x 2 batch
static constexpr int CBC  = 262;    // 2*128 + 6
static constexpr int BSTR = 264;    // padded bct row stride (floats), 16B-aligned

typedef float f32x4  __attribute__((ext_vector_type(4)));
typedef short bf16x8 __attribute__((ext_vector_type(8)));
typedef short bf16x4v __attribute__((ext_vector_type(4)));

DEV int map_l(int s, int k) {
    int m = (k & 2) ? (4095 - s) : s;
    if (k & 1) m = ((m & 63) << 6) | (m >> 6);
    return m;
}
DEV float silu_f(float x) { return x / (1.f + __expf(-x)); }
DEV short f2bf(float f) {
    union { __hip_bfloat16 h; short s; } u;
    u.h = __float2bfloat16(f);
    return u.s;
}
DEV float bf2f(short s) {
    return __uint_as_float(((unsigned)(unsigned short)s) << 16);
}
DEV bf16x8 pack8(float4 a, float4 b) {
    bf16x8 r;
    r[0]=f2bf(a.x); r[1]=f2bf(a.y); r[2]=f2bf(a.z); r[3]=f2bf(a.w);
    r[4]=f2bf(b.x); r[5]=f2bf(b.y); r[6]=f2bf(b.z); r[7]=f2bf(b.w);
    return r;
}
// 8-B-aligned bf16x8 load (two dwordx2) for reversed-direction bases
DEV bf16x8 load8u(const __hip_bfloat16* p) {
    bf16x4v lo = *(const bf16x4v*)p;
    bf16x4v hi = *(const bf16x4v*)(p + 4);
    bf16x8 r;
    r[0]=lo[0]; r[1]=lo[1]; r[2]=lo[2]; r[3]=lo[3];
    r[4]=hi[0]; r[5]=hi[1]; r[6]=hi[2]; r[7]=hi[3];
    return r;
}
DEV void store16(__hip_bfloat16* p, const float* v) {
    bf16x8 a, b;
    #pragma unroll
    for (int e = 0; e < 8; ++e) { a[e] = f2bf(v[e]); b[e] = f2bf(v[8+e]); }
    *(bf16x8*)p = a;
    *((bf16x8*)p + 1) = b;
}
DEV void storeT(float v, float* p) { *p = v; }
DEV void storeT(float v, __hip_bfloat16* p) { *p = __float2bfloat16(v); }

__global__ void sentinel_k(float* out) { out[0] = 1e30f; }

// ---------------- fused weight transposes -> bf16 Wt[n][k] blocks ----------------
// layout: skip[384*192] | xs[384*192] | bcdt[320*192, zero-pad n>=262] | out[192*384]
__global__ void wt_all_k(const float* __restrict__ W_skip, const float* __restrict__ W_xs,
                         const float* __restrict__ W_bcdt, const float* __restrict__ W_out,
                         __hip_bfloat16* __restrict__ Wt)
{
    int idx = blockIdx.x * 256 + threadIdx.x;
    if (idx < 73728) {
        int n = idx / 192, k = idx - n * 192;
        Wt[idx] = __float2bfloat16(W_skip[(size_t)k * 384 + n]);
    } else if (idx < 147456) {
        int r = idx - 73728;
        int n = r / 192, k = r - n * 192;
        Wt[idx] = __float2bfloat16(W_xs[(size_t)k * 384 + n]);
    } else if (idx < 208896) {
        int r = idx - 147456;
        int n = r / 192, k = r - n * 192;
        Wt[idx] = __float2bfloat16(n < 262 ? W_bcdt[(size_t)k * 262 + n] : 0.f);
    } else if (idx < 282624) {
        int r = idx - 208896;
        int n = r / 384, k = r - n * 384;
        Wt[idx] = __float2bfloat16(W_out[(size_t)k * 192 + n]);
    }
}

// ---------------- MFMA GEMM: MODE 0 plain, 1 silu, 2 dual (cols<384 silu->C, >=384 plain->C2) ----------------
template<int MODE, typename AT, typename OutT>
__global__ __launch_bounds__(256) void mgemm_k(
    const AT* __restrict__ A0, const AT* __restrict__ A1,
    const __hip_bfloat16* __restrict__ Wt, OutT* __restrict__ C,
    OutT* __restrict__ C2, int N, int Kd)
{
    int i0 = blockIdx.y * 128;
    int j0 = blockIdx.x * 64;
    int t = threadIdx.x;
    int w = t >> 6, lane = t & 63;
    int lr = lane & 15, kq = lane >> 4;
    const AT* arow[2];
    #pragma unroll
    for (int a = 0; a < 2; ++a) {
        int grow = i0 + w * 32 + a * 16 + lr;
        const AT* Ap = (grow < 8192) ? A0 : A1;
        arow[a] = Ap + (size_t)(grow & 8191) * Kd;
    }
    f32x4 acc[2][4] = {};
    for (int k0 = 0; k0 < Kd; k0 += 32) {
        int kb = k0 + kq * 8;
        bf16x8 af[2];
        #pragma unroll
        for (int a = 0; a < 2; ++a) {
            if constexpr (sizeof(AT) == 4)
                af[a] = pack8(*(const float4*)(arow[a] + kb), *(const float4*)(arow[a] + kb + 4));
            else
                af[a] = *(const bf16x8*)(arow[a] + kb);
        }
        #pragma unroll
        for (int b = 0; b < 4; ++b) {
            int n = j0 + b * 16 + lr;
            bf16x8 bfr = *(const bf16x8*)(Wt + (size_t)n * Kd + kb);
            #pragma unroll
            for (int a = 0; a < 2; ++a)
                acc[a][b] = __builtin_amdgcn_mfma_f32_16x16x32_bf16(af[a], bfr, acc[a][b], 0, 0, 0);
        }
    }
    #pragma unroll
    for (int a = 0; a < 2; ++a)
        #pragma unroll
        for (int b = 0; b < 4; ++b)
            #pragma unroll
            for (int r = 0; r < 4; ++r) {
                int row = i0 + w * 32 + a * 16 + kq * 4 + r;
                int col = j0 + b * 16 + lr;
                float v = acc[a][b][r];
                if constexpr (MODE == 0) {
                    if (col < N) storeT(v, &C[(size_t)row * N + col]);
                } else if constexpr (MODE == 1) {
                    if (col < N) storeT(silu_f(v), &C[(size_t)row * N + col]);
                } else {
                    if (col < 384) storeT(silu_f(v), &C[(size_t)row * 384 + col]);
                    else           storeT(v, &C2[(size_t)row * 384 + col - 384]);
                }
            }
}

// ---------------- depthwise 3x3 conv (pad 1) + bias + silu ----------------
template<typename InT, typename OutT>
__global__ void dwconv_k(const InT* __restrict__ in, const float* __restrict__ w,
                         const float* __restrict__ bias, OutT* __restrict__ out,
                         int Cin, int Cout)
{
    int idx = blockIdx.x * 256 + threadIdx.x;
    int total = GG * LL * Cin;
    if (idx >= total) return;
    int c = idx % Cin;
    int l = (idx / Cin) % LL;
    int g = idx / (Cin * LL);
    int h = l >> 6, ww = l & 63;
    float acc = bias[c];
    #pragma unroll
    for (int dy = 0; dy < 3; ++dy) {
        int hh = h + dy - 1;
        if ((unsigned)hh >= 64u) continue;
        #pragma unroll
        for (int dx = 0; dx < 3; ++dx) {
            int wx = ww + dx - 1;
            if ((unsigned)wx >= 64u) continue;
            float iv;
            if constexpr (sizeof(InT) == 4) iv = in[((size_t)g * LL + (hh << 6) + wx) * Cin + c];
            else iv = __bfloat162float(in[((size_t)g * LL + (hh << 6) + wx) * Cin + c]);
            acc += iv * w[c * 9 + dy * 3 + dx];
        }
    }
    storeT(silu_f(acc), &out[((size_t)g * LL + l) * Cout + c]);
}

// ---------------- xs transpose/gather: XtG[g][kd01][pc 384][s 4096] bf16 (2 dirs only) ----------------
__global__ __launch_bounds__(256) void xt_k(const __hip_bfloat16* __restrict__ xs8,
                                            __hip_bfloat16* __restrict__ XtG)
{
    __shared__ float ls[16][17][17];
    int bid = blockIdx.x;                 // 24 pct x 4 wt x 4 ht x 4 g = 1536
    int pct = bid % 24;
    int rest = bid / 24;
    int wt = rest & 3, ht2 = (rest >> 2) & 3, g = rest >> 4;
    int h0 = ht2 * 16, w0 = wt * 16, pc0 = pct * 16;
    int t = threadIdx.x;
    int pcl = t & 15, hwb = t >> 4;
    #pragma unroll
    for (int r = 0; r < 16; ++r) {
        int hw = hwb + r * 16;
        int h = hw >> 4, w2 = hw & 15;
        ls[h][w2][pcl] = __bfloat162float(
            xs8[((size_t)g * LL + (h0 + h) * 64 + (w0 + w2)) * 384 + pc0 + pcl]);
    }
    __syncthreads();
    int pc = t >> 4, q = t & 15;
    float v[16];
    size_t rowbase;
    // kd0: s = (h0+q)*64 + w0 + e
    #pragma unroll
    for (int e = 0; e < 16; ++e) v[e] = ls[q][e][pc];
    rowbase = ((size_t)(g * 2 + 0) * 384 + pc0 + pc) * 4096;
    store16(XtG + rowbase + (h0 + q) * 64 + w0, v);
    // kd1: s = (w0+q)*64 + h0 + e
    #pragma unroll
    for (int e = 0; e < 16; ++e) v[e] = ls[e][q][pc];
    rowbase = ((size_t)(g * 2 + 1) * 384 + pc0 + pc) * 4096;
    store16(XtG + rowbase + (w0 + q) * 64 + h0, v);
}

// ---------------- B transpose/gather: Bt[g][n 512][s 4096] bf16 (all 4 dirs) ----------------
__global__ __launch_bounds__(256) void bt_k(const float* __restrict__ bct,
                                            __hip_bfloat16* __restrict__ Bt)
{
    __shared__ float ls[16][17][17];
    int bid = blockIdx.x;                 // 32 nt x 4 wt x 4 ht x 4 g = 2048
    int nt = bid & 31;
    int rest = bid >> 5;
    int wt = rest & 3, ht2 = (rest >> 2) & 3, g = rest >> 4;
    int h0 = ht2 * 16, w0 = wt * 16;
    int kd = nt >> 3, ch0 = (nt & 7) * 16;
    int t = threadIdx.x;
    int cl = t & 15, hwb = t >> 4;
    #pragma unroll
    for (int r = 0; r < 16; ++r) {
        int hw = hwb + r * 16;
        int h = hw >> 4, w2 = hw & 15;
        ls[h][w2][cl] = bct[((size_t)g * LL + (h0 + h) * 64 + (w0 + w2)) * BSTR + ch0 + cl];
    }
    __syncthreads();
    int pc = t >> 4, q = t & 15;
    int n = nt * 16 + pc;
    __hip_bfloat16* rowp = Bt + ((size_t)g * 512 + n) * 4096;
    float v[16];
    if (kd == 0) {
        #pragma unroll
        for (int e = 0; e < 16; ++e) v[e] = ls[q][e][pc];
        store16(rowp + (h0 + q) * 64 + w0, v);
    } else if (kd == 1) {
        #pragma unroll
        for (int e = 0; e < 16; ++e) v[e] = ls[e][q][pc];
        store16(rowp + (w0 + q) * 64 + h0, v);
    } else if (kd == 2) {
        #pragma unroll
        for (int e = 0; e < 16; ++e) v[e] = ls[q][15 - e][pc];
        store16(rowp + 4095 - (h0 + q) * 64 - w0 - 15, v);
    } else {
        #pragma unroll
        for (int e = 0; e < 16; ++e) v[e] = ls[15 - e][q][pc];
        store16(rowp + 4095 - (w0 + q) * 64 - h0 - 15, v);
    }
}

// ---------------- C_scan[g][s 4096][n 256] bf16 (kd0/kd1 C-channels; kd2/3 read row 4095-s) ----------------
__global__ __launch_bounds__(256) void cs_k(const float* __restrict__ bct,
                                            __hip_bfloat16* __restrict__ Cs)
{
    __shared__ float ls[16][16][17];
    int bid = blockIdx.x;                 // 16 ct x 4 wt x 4 ht x 4 g = 1024
    int ct = bid & 15;
    int rest = bid >> 4;
    int wt = rest & 3, ht2 = (rest >> 2) & 3, g = rest >> 4;
    int h0 = ht2 * 16, w0 = wt * 16;
    int kd = ct >> 3, ch0 = (ct & 7) * 16;   // C channels at bct offset 128+ch0
    int t = threadIdx.x;
    int cl = t & 15, hwb = t >> 4;
    #pragma unroll
    for (int r = 0; r < 16; ++r) {
        int hw = hwb + r * 16;
        int h = hw >> 4, w2 = hw & 15;
        ls[h][w2][cl] = bct[((size_t)g * LL + (h0 + h) * 64 + (w0 + w2)) * BSTR + 128 + ch0 + cl];
    }
    __syncthreads();
    int h = t >> 4, w2 = t & 15;
    int s = (kd == 0) ? (h0 + h) * 64 + (w0 + w2) : (w0 + w2) * 64 + (h0 + h);
    float v[16];
    #pragma unroll
    for (int e = 0; e < 16; ++e) v[e] = ls[h][w2][e];
    store16(Cs + ((size_t)g * 4096 + s) * 256 + kd * 128 + ch0, v);
}

// ---------------- dt softplus + per-chunk inclusive cumsum of dt*A (shuffle scan) ----------------
__global__ __launch_bounds__(256) void dtscan_k(
    const float* __restrict__ bct, const float* __restrict__ dt_bias,
    const float* __restrict__ A_logs, float* __restrict__ dt_arr,
    float* __restrict__ ac_arr, float* __restrict__ cdecay)
{
    int bid = blockIdx.x;                 // ht + 24*(c + 16*g) = 1536
    int ht = bid % 24;
    int gc = bid / 24;
    int c = gc & 15, g = gc >> 4;
    int k = ht / 6, h = ht % 6;
    int t = threadIdx.x;
    int s = c * 256 + t;
    int l = map_l(s, k);
    float raw = bct[((size_t)g * LL + l) * BSTR + 256 + h] + dt_bias[ht];
    float dtv = raw > 20.f ? raw : log1pf(__expf(raw));
    float dA = dtv * (-__expf(A_logs[ht]));
    float v = dA;
    #pragma unroll
    for (int off = 1; off < 64; off <<= 1) {
        float u = __shfl_up(v, off);
        if ((t & 63) >= off) v += u;
    }
    __shared__ float wsum[4];
    if ((t & 63) == 63) wsum[t >> 6] = v;
    __syncthreads();
    float add = 0.f;
    #pragma unroll
    for (int w2 = 0; w2 < 3; ++w2)
        if (w2 < (t >> 6)) add += wsum[w2];
    float cum = v + add;
    size_t base = ((size_t)g * 24 + ht) * LL + s;
    dt_arr[base] = dtv;
    ac_arr[base] = cum;
    if (t == 255) cdecay[(g * 24 + ht) * 16 + c] = __expf(cum);
}

// ---------------- MFMA CB: CB[gc][i][j] = sum_n C[i,n]*B[j,n] (bf16 out) ----------------
__global__ __launch_bounds__(256) void cb_k(const float* __restrict__ bct,
                                            const __hip_bfloat16* __restrict__ Cs,
                                            __hip_bfloat16* __restrict__ CBm)
{
    int bid = blockIdx.x;                 // gc*4 + jq, 256 blocks
    int jq = bid & 3;
    int gc = bid >> 2;
    int c = gc & 15, g = gc >> 4;
    int t = threadIdx.x;
    int w = t >> 6, lane = t & 63;
    int lr = lane & 15, kq = lane >> 4;
    const float* bg = bct + (size_t)g * LL * BSTR;
    const __hip_bfloat16* cg = Cs + (size_t)g * 4096 * 256;
    f32x4 acc[4][4] = {};
    for (int ks = 0; ks < 16; ++ks) {
        int n0 = ks * 32 + kq * 8;
        int kd = n0 >> 7, nn = n0 & 127;
        bf16x8 bfr[4];
        #pragma unroll
        for (int jt = 0; jt < 4; ++jt) {
            int j = jq * 64 + jt * 16 + lr;
            int l = map_l(c * 256 + j, kd);
            const float* p = bg + (size_t)l * BSTR + nn;
            bfr[jt] = pack8(*(const float4*)p, *(const float4*)(p + 4));
        }
        #pragma unroll
        for (int iq = 0; iq < 4; ++iq) {
            int i = (w * 4 + iq) * 16 + lr;
            int s = c * 256 + i;
            int row = (kd < 2) ? s : 4095 - s;
            int col = ((kd & 1) << 7) + nn;
            bf16x8 af = *(const bf16x8*)(cg + (size_t)row * 256 + col);
            #pragma unroll
            for (int jt = 0; jt < 4; ++jt)
                acc[iq][jt] = __builtin_amdgcn_mfma_f32_16x16x32_bf16(af, bfr[jt], acc[iq][jt], 0, 0, 0);
        }
    }
    __hip_bfloat16* ob = CBm + (size_t)gc * 65536;
    #pragma unroll
    for (int iq = 0; iq < 4; ++iq)
        #pragma unroll
        for (int jt = 0; jt < 4; ++jt)
            #pragma unroll
            for (int r = 0; r < 4; ++r) {
                int i = (w * 4 + iq) * 16 + kq * 4 + r;
                int j = jq * 64 + jt * 16 + lr;
                ob[(size_t)i * 256 + j] = __float2bfloat16(acc[iq][jt][r]);
            }
}

// ---------------- MFMA states: S[p,n] = sum_j w_j x[j,p] B[j,n] ----------------
__global__ __launch_bounds__(256) void states_k(
    const __hip_bfloat16* __restrict__ XtG, const __hip_bfloat16* __restrict__ Bt,
    const float* __restrict__ dt_arr, const float* __restrict__ ac_arr,
    __hip_bfloat16* __restrict__ states)
{
    __shared__ float wsh[256];
    int task = (blockIdx.x & 7) * 192 + (blockIdx.x >> 3);  // XCD swizzle (perf only)
    int ht = task % 24;
    int gc = task / 24;
    int c = gc & 15, g = gc >> 4;
    int kd = ht / 6;
    bool rev = kd >= 2;
    int c0 = (ht % 6) * 64;
    int t = threadIdx.x;
    int w = t >> 6, lane = t & 63;
    int lr = lane & 15, kq = lane >> 4;
    const float* dtp = dt_arr + ((size_t)g * 24 + ht) * LL + c * 256;
    const float* acp = ac_arr + ((size_t)g * 24 + ht) * LL + c * 256;
    float ac_last = acp[255];
    wsh[t] = __expf(ac_last - acp[t]) * dtp[t];
    __syncthreads();
    const __hip_bfloat16* xg = XtG + ((size_t)(g * 2 + (kd & 1)) * 384 + c0) * 4096;
    const __hip_bfloat16* btg = Bt + (size_t)g * 512 * 4096;
    f32x4 acc[4][8] = {};
    for (int ks = 0; ks < 8; ++ks) {
        int j0 = ks * 32 + kq * 8;
        bf16x8 af[4];
        #pragma unroll
        for (int pt = 0; pt < 4; ++pt) {
            size_t rowoff = (size_t)(pt * 16 + lr) * 4096;
            if (!rev) {
                bf16x8 xv = *(const bf16x8*)(xg + rowoff + c * 256 + j0);
                #pragma unroll
                for (int e = 0; e < 8; ++e) af[pt][e] = f2bf(bf2f(xv[e]) * wsh[j0 + e]);
            } else {
                bf16x8 xv = load8u(xg + rowoff + 4088 - c * 256 - j0);
                #pragma unroll
                for (int e = 0; e < 8; ++e) af[pt][e] = f2bf(bf2f(xv[7 - e]) * wsh[j0 + e]);
            }
        }
        #pragma unroll
        for (int nt = 0; nt < 8; ++nt) {
            int n = (w * 8 + nt) * 16 + lr;
            bf16x8 bv = *(const bf16x8*)(btg + (size_t)n * 4096 + c * 256 + j0);
            #pragma unroll
            for (int pt = 0; pt < 4; ++pt)
                acc[pt][nt] = __builtin_amdgcn_mfma_f32_16x16x32_bf16(af[pt], bv, acc[pt][nt], 0, 0, 0);
        }
    }
    __hip_bfloat16* ob = states + ((size_t)gc * 24 + ht) * 32768;
    #pragma unroll
    for (int pt = 0; pt < 4; ++pt)
        #pragma unroll
        for (int nt = 0; nt < 8; ++nt)
            #pragma unroll
            for (int r = 0; r < 4; ++r) {
                int p = pt * 16 + kq * 4 + r;
                int n = (w * 8 + nt) * 16 + lr;
                ob[(size_t)p * 512 + n] = __float2bfloat16(acc[pt][nt][r]);
            }
}

// ---------------- inter-chunk scan, in place ----------------
__global__ void scan_k(__hip_bfloat16* __restrict__ states, const float* __restrict__ cdecay)
{
    int idx = blockIdx.x * 256 + threadIdx.x;
    int g = idx / 786432;
    int r = idx - g * 786432;
    int ht = r >> 15;
    int pn = r & 32767;
    const float* cd = cdecay + (g * 24 + ht) * 16;
    __hip_bfloat16* base = states + ((size_t)g * 384 + ht) * 32768 + pn;
    float S = 0.f;
    #pragma unroll
    for (int c2 = 0; c2 < 16; ++c2) {
        __hip_bfloat16* p = base + (size_t)c2 * 786432;
        float tmp = __bfloat162float(*p);
        *p = __float2bfloat16(S);
        S = S * cd[c2] + tmp;
    }
}

// ---------------- MFMA y -> per-direction y4[g][kd][s][384] bf16 (coalesced, no atomics) ----------------
__global__ __launch_bounds__(256) void yk(
    const __hip_bfloat16* __restrict__ XtG, const __hip_bfloat16* __restrict__ Cs,
    const __hip_bfloat16* __restrict__ CBm, const __hip_bfloat16* __restrict__ prev,
    const float* __restrict__ dt_arr, const float* __restrict__ ac_arr,
    const float* __restrict__ Ds, __hip_bfloat16* __restrict__ y4)
{
    __shared__ float acs[256], dts[256], ejdt[256];
    int task = (blockIdx.x & 7) * 192 + (blockIdx.x >> 3);  // XCD swizzle (perf only)
    int ht = task % 24;
    int gc = task / 24;
    int c = gc & 15, g = gc >> 4;
    int kd = ht / 6;
    bool rev = kd >= 2;
    int c0 = (ht % 6) * 64;
    int t = threadIdx.x;
    int w = t >> 6, lane = t & 63;
    int lr = lane & 15, kq = lane >> 4;
    acs[t] = ac_arr[((size_t)g * 24 + ht) * LL + c * 256 + t];
    dts[t] = dt_arr[((size_t)g * 24 + ht) * LL + c * 256 + t];
    __syncthreads();
    // ejdt[j] = exp(ac_blockstart(j) - ac_j) * dt_j   (32-aligned blocks; args <= 0, no overflow)
    ejdt[t] = __expf(acs[t & ~31] - acs[t]) * dts[t];
    __syncthreads();
    const __hip_bfloat16* xg = XtG + ((size_t)(g * 2 + (kd & 1)) * 384 + c0) * 4096;
    const __hip_bfloat16* cbb = CBm + (size_t)gc * 65536;
    const __hip_bfloat16* cg = Cs + (size_t)g * 4096 * 256;
    f32x4 acc[4][4] = {};
    // ---- term2 FIRST (unscaled): C @ prev^T ----
    const __hip_bfloat16* pv = prev + ((size_t)gc * 24 + ht) * 32768;
    #pragma unroll 2
    for (int ns = 0; ns < 16; ++ns) {
        int n0 = ns * 32 + kq * 8;
        int kd2 = n0 >> 7, nn = n0 & 127;
        int col = ((kd2 & 1) << 7) + nn;
        bf16x8 pb[4];
        #pragma unroll
        for (int pt = 0; pt < 4; ++pt)
            pb[pt] = *(const bf16x8*)(pv + (size_t)(pt * 16 + lr) * 512 + n0);
        #pragma unroll
        for (int q = 0; q < 4; ++q) {
            int i = (w + 4 * q) * 16 + lr;
            int s = c * 256 + i;
            int row = (kd2 < 2) ? s : 4095 - s;
            bf16x8 af = *(const bf16x8*)(cg + (size_t)row * 256 + col);
            #pragma unroll
            for (int pt = 0; pt < 4; ++pt)
                acc[q][pt] = __builtin_amdgcn_mfma_f32_16x16x32_bf16(af, pb[pt], acc[q][pt], 0, 0, 0);
        }
    }
    // ---- scale term2 by exp(ac_i) in place ----
    #pragma unroll
    for (int q = 0; q < 4; ++q)
        #pragma unroll
        for (int r = 0; r < 4; ++r) {
            float er = __expf(acs[(w + 4 * q) * 16 + kq * 4 + r]);
            #pragma unroll
            for (int pt = 0; pt < 4; ++pt) acc[q][pt][r] *= er;
        }
    // ---- term1: causal M @ x; M = CB * exp(ac_i-ac_b) * ejdt ----
    float aci_q[4];
    #pragma unroll
    for (int q = 0; q < 4; ++q) aci_q[q] = acs[(w + 4 * q) * 16 + lr];
    for (int ks = 0; ks < 8; ++ks) {
        int j0 = ks * 32 + kq * 8;
        bf16x8 xb[4];
        #pragma unroll
        for (int pt = 0; pt < 4; ++pt) {
            size_t rowoff = (size_t)(pt * 16 + lr) * 4096;
            xb[pt] = rev ? load8u(xg + rowoff + 4088 - c * 256 - j0)
                         : *(const bf16x8*)(xg + rowoff + c * 256 + j0);
        }
        float acb = acs[ks * 32];
        float ej[8];
        #pragma unroll
        for (int e = 0; e < 8; ++e) ej[e] = ejdt[j0 + e];
        #pragma unroll
        for (int q = 0; q < 4; ++q) {
            int rt = w + 4 * q;
            if (ks * 32 > rt * 16 + 15) continue;        // whole j-block above diagonal
            int i = rt * 16 + lr;
            float r2 = __expf(aci_q[q] - acb);
            bf16x8 cb8 = *(const bf16x8*)(cbb + (size_t)i * 256 + j0);
            bf16x8 af;
            #pragma unroll
            for (int e = 0; e < 8; ++e) {
                int jj = rev ? (j0 + 7 - e) : (j0 + e);   // element e of xb holds j=jj
                float coef = r2 * ej[jj - j0] * bf2f(cb8[jj - j0]);
                af[e] = (jj <= i) ? f2bf(coef) : (short)0;
            }
            #pragma unroll
            for (int pt = 0; pt < 4; ++pt)
                acc[q][pt] = __builtin_amdgcn_mfma_f32_16x16x32_bf16(af, xb[pt], acc[q][pt], 0, 0, 0);
        }
    }
    // ---- epilogue: + Ds*x, coalesced bf16 store to y4 (scan order) ----
    float Dsv = Ds[ht];
    __hip_bfloat16* yb = y4 + (((size_t)(g * 4 + kd) * 4096 + c * 256) * 384) + c0;
    #pragma unroll
    for (int q = 0; q < 4; ++q) {
        int rt = w + 4 * q;
        #pragma unroll
        for (int pt = 0; pt < 4; ++pt) {
            int p = pt * 16 + lr;
            int ibase = rt * 16 + kq * 4;
            size_t sa = rev ? (size_t)(4092 - c * 256 - ibase) : (size_t)(c * 256 + ibase);
            bf16x4v x4 = *(const bf16x4v*)(xg + (size_t)p * 4096 + sa);
            #pragma unroll
            for (int r = 0; r < 4; ++r) {
                int i = ibase + r;
                float xv = bf2f(x4[rev ? 3 - r : r]);
                yb[(size_t)i * 384 + p] = __float2bfloat16(acc[q][pt][r] + Dsv * xv);
            }
        }
    }
}

// ---------------- merge 4 directions + gate + RMSNorm -> gn bf16 ----------------
__global__ __launch_bounds__(128) void gate_k(
    const __hip_bfloat16* __restrict__ y4, const __hip_bfloat16* __restrict__ z_silu,
    const float* __restrict__ norm_w, __hip_bfloat16* __restrict__ gn)
{
    int g = blockIdx.x >> 12;
    int l = blockIdx.x & 4095;
    int t = threadIdx.x;
    int Tl = ((l & 63) << 6) | (l >> 6);
    const __hip_bfloat16* p0 = y4 + ((size_t)(g * 4 + 0) * 4096 + l) * 384;
    const __hip_bfloat16* p1 = y4 + ((size_t)(g * 4 + 1) * 4096 + Tl) * 384;
    const __hip_bfloat16* p2 = y4 + ((size_t)(g * 4 + 2) * 4096 + 4095 - l) * 384;
    const __hip_bfloat16* p3 = y4 + ((size_t)(g * 4 + 3) * 4096 + 4095 - Tl) * 384;
    const __hip_bfloat16* zp = z_silu + ((size_t)g * LL + l) * 384;
    float gc[3]; float ssq = 0.f;
    #pragma unroll
    for (int q = 0; q < 3; ++q) {
        int cdim = t + 128 * q;
        float yf = __bfloat162float(p0[cdim]) + __bfloat162float(p1[cdim]) +
                   __bfloat162float(p2[cdim]) + __bfloat162float(p3[cdim]);
        float v = yf * __bfloat162float(zp[cdim]);
        gc[q] = v;
        ssq += v * v;
    }
    float v = ssq;
    #pragma unroll
    for (int off = 32; off > 0; off >>= 1) v += __shfl_down(v, off);
    __shared__ float tot[2];
    if ((t & 63) == 0) tot[t >> 6] = v;
    __syncthreads();
    float rs = rsqrtf((tot[0] + tot[1]) * (1.f / 384.f) + 1e-5f);
    __hip_bfloat16* gp = gn + ((size_t)g * LL + l) * 384;
    #pragma unroll
    for (int q = 0; q < 3; ++q) {
        int cdim = t + 128 * q;
        gp[cdim] = __float2bfloat16(gc[q] * rs * norm_w[cdim]);
    }
}

extern "C" void kernel_launch(void* const* d_in, const int* in_sizes, int n_in,
                              void* d_out, int out_size, void* d_ws, size_t ws_size,
                              hipStream_t stream)
{
    const float* u1      = (const float*)d_in[0];
    const float* u2      = (const float*)d_in[1];
    const float* u21     = (const float*)d_in[2];
    const float* u12     = (const float*)d_in[3];
    const float* W_skip  = (const float*)d_in[4];
    const float* W_xs    = (const float*)d_in[5];
    const float* W_bcdt  = (const float*)d_in[6];
    const float* cxw     = (const float*)d_in[7];
    const float* cxb     = (const float*)d_in[8];
    const float* cbw     = (const float*)d_in[9];
    const float* cbb     = (const float*)d_in[10];
    const float* dt_bias = (const float*)d_in[11];
    const float* A_logs  = (const float*)d_in[12];
    const float* Ds      = (const float*)d_in[13];
    const float* norm_w  = (const float*)d_in[14];
    const float* W_out   = (const float*)d_in[15];
    float* out = (float*)d_out;

    char* w = (char*)d_ws;
    // static layout (bytes)
    size_t o_y4  = 0;                         // 50,331,648 bf16 y4 (early: bct@0, xs8@17.3M)
    size_t o_st  = o_y4 + 50331648;           // 100,663,296 bf16 states (early: pre_bc@0, pre_xs@8.65M; late: gn@0)
    size_t o_z   = o_st + 100663296;          // 12,582,912 bf16 z_silu
    size_t o_xtg = o_z  + 12582912;           // 25,165,824 bf16 XtG (2 dirs)
    size_t o_bt  = o_xtg + 25165824;          // 16,777,216 bf16 Bt
    size_t o_cs  = o_bt + 16777216;           //  8,388,608 bf16 C_scan
    size_t o_cbm = o_cs + 8388608;            //  8,388,608 bf16 CBm
    size_t o_dt  = o_cbm + 8388608;           //  1,572,864 f32 dt_arr
    size_t o_ac  = o_dt + 1572864;            //  1,572,864 f32 ac_arr
    size_t o_cd  = o_ac + 1572864;            //      8,192 f32 cdecay
    size_t o_wt  = o_cd + 8192;               //    589,824 bf16 Wt (skip|xs|bcdt|out)
    size_t total = o_wt + 589824;             // = 226,041,856 B (< proven 238.5 MB)
    if (total > ws_size) {
        sentinel_k<<<1, 1, 0, stream>>>(out); // absmax ~1e30 => workspace too small
        return;
    }
    __hip_bfloat16* y4     = (__hip_bfloat16*)(w + o_y4);
    __hip_bfloat16* states = (__hip_bfloat16*)(w + o_st);
    __hip_bfloat16* z_silu = (__hip_bfloat16*)(w + o_z);
    __hip_bfloat16* XtG    = (__hip_bfloat16*)(w + o_xtg);
    __hip_bfloat16* Bt     = (__hip_bfloat16*)(w + o_bt);
    __hip_bfloat16* Cs     = (__hip_bfloat16*)(w + o_cs);
    __hip_bfloat16* CBm    = (__hip_bfloat16*)(w + o_cbm);
    float*          dt_arr = (float*)(w + o_dt);
    float*          ac_arr = (float*)(w + o_ac);
    float*          cdecay = (float*)(w + o_cd);
    __hip_bfloat16* Wt     = (__hip_bfloat16*)(w + o_wt);
    __hip_bfloat16* Wt_skip = Wt;                       // n 0..383 (and xs at 384..767, contiguous)
    __hip_bfloat16* Wt_bcdt = Wt + 147456;
    __hip_bfloat16* Wt_out  = Wt + 208896;
    // transient aliases
    float*          bct    = (float*)(w + o_y4);                  // dead after cb_k (< yk)
    __hip_bfloat16* xs8    = (__hip_bfloat16*)(w + o_y4 + 17301504); // dead after xt_k
    __hip_bfloat16* pre_bc = (__hip_bfloat16*)(w + o_st);         // dead after dwconv_bc
    __hip_bfloat16* pre_xs = (__hip_bfloat16*)(w + o_st + 8650752); // dead after dwconv_xs
    __hip_bfloat16* gn     = (__hip_bfloat16*)(w + o_st);         // written by gate (states dead)

    dim3 blk(256);
    // 0. fused weight transposes
    wt_all_k<<<dim3(1104), blk, 0, stream>>>(W_skip, W_xs, W_bcdt, W_out, Wt);
    // 1. input GEMMs (MFMA): skip+xs fused (N=768 dual-out), bcdt separate
    mgemm_k<2, float, __hip_bfloat16><<<dim3(12, 128), blk, 0, stream>>>(
        u1, u2, Wt_skip, z_silu, pre_xs, 768, 192);
    mgemm_k<0, float, __hip_bfloat16><<<dim3(5, 128), blk, 0, stream>>>(
        u21, u12, Wt_bcdt, pre_bc, nullptr, CBC, 192);
    // 2. depthwise conv + silu
    dwconv_k<__hip_bfloat16, __hip_bfloat16><<<dim3((GG * LL * 384) / 256), blk, 0, stream>>>(
        pre_xs, cxw, cxb, xs8, 384, 384);
    dwconv_k<__hip_bfloat16, float><<<dim3((GG * LL * CBC) / 256), blk, 0, stream>>>(
        pre_bc, cbw, cbb, bct, CBC, BSTR);
    // 3. transposed/gathered bf16 operand tensors
    xt_k<<<dim3(1536), blk, 0, stream>>>(xs8, XtG);
    bt_k<<<dim3(2048), blk, 0, stream>>>(bct, Bt);
    cs_k<<<dim3(1024), blk, 0, stream>>>(bct, Cs);
    // 4. dt softplus + per-chunk cumsum
    dtscan_k<<<dim3(1536), blk, 0, stream>>>(bct, dt_bias, A_logs, dt_arr, ac_arr, cdecay);
    // 5. CB = C·B^T (MFMA)
    cb_k<<<dim3(256), blk, 0, stream>>>(bct, Cs, CBm);
    // 6. per-chunk states (MFMA, XCD-swizzled)
    states_k<<<dim3(1536), blk, 0, stream>>>(XtG, Bt, dt_arr, ac_arr, states);
    // 7. inter-chunk scan
    scan_k<<<dim3(12288), blk, 0, stream>>>(states, cdecay);
    // 8. y (MFMA, XCD-swizzled) -> per-direction y4
    yk<<<dim3(1536), blk, 0, stream>>>(XtG, Cs, CBm, states, dt_arr, ac_arr, Ds, y4);
    // 9. merge directions + gate + RMSNorm -> gn bf16
    gate_k<<<dim3(16384), dim3(128), 0, stream>>>(y4, z_silu, norm_w, gn);
    // 10. output GEMM (MFMA, bf16 A)
    mgemm_k<0, __hip_bfloat16, float><<<dim3(3, 128), blk, 0, stream>>>(
        gn, gn + (size_t)8192 * 384, Wt_out, out, nullptr, 192, 384);
}